// Round 1
// 367.312 us; speedup vs baseline: 1.0489x; 1.0489x over previous
//
#include <hip/hip_runtime.h>
#include <hip/hip_fp16.h>
#include <math.h>

#define NN 100000
#define EE 1600000
#define ET (EE + NN)   // 1,700,000 edges incl self-loops
#define FIN 128
#define D1 64          // H1*C1
#define H1 8
#define C1 8
#define C2 40
#define NEG 0.2f
#define EPSV 1e-16f
#define LOG2E 1.4426950408889634f

#define NBKT 196       // buckets of 512 dst: (99999>>9)+1
#define CHUNK 8192     // edges per scatter block
#define NBB ((ET + CHUNK - 1) / CHUNK)

__device__ __forceinline__ void edge_sd(int e, const int* __restrict__ ei, int& s, int& d) {
  if (e < EE) { s = ei[e]; d = ei[EE + e]; }
  else        { s = e - EE; d = s; }
}

// ---------- CSR build: bucket histogram ----------
__global__ __launch_bounds__(256) void hist_kernel(const int* __restrict__ ei,
                                                   int* __restrict__ ghist) {
  __shared__ int lh[NBKT];
  int t = threadIdx.x;
  if (t < NBKT) lh[t] = 0;
  __syncthreads();
  for (int e = blockIdx.x * 256 + t; e < ET; e += gridDim.x * 256) {
    int d = (e < EE) ? ei[EE + e] : e - EE;
    atomicAdd(&lh[d >> 9], 1);
  }
  __syncthreads();
  if (t < NBKT && lh[t]) atomicAdd(&ghist[t], lh[t]);
}

__global__ __launch_bounds__(256) void bscan_kernel(const int* __restrict__ ghist,
                                                    int* __restrict__ bbase) {
  __shared__ int sd[256];
  int t = threadIdx.x;
  int v = (t < NBKT) ? ghist[t] : 0;
  sd[t] = v;
  __syncthreads();
  for (int off = 1; off < 256; off <<= 1) {
    int x = sd[t];
    int y = (t >= off) ? sd[t - off] : 0;
    __syncthreads();
    sd[t] = x + y;
    __syncthreads();
  }
  int excl = sd[t] - v;
  if (t < NBKT) bbase[t] = excl;
  if (t == NBKT - 1) bbase[NBKT] = excl + v;
}

// ---------- scatter edges into bucket array (run-reserved, write-local) ----------
__global__ __launch_bounds__(256) void scatter_kernel(const int* __restrict__ ei,
                                                      const int* __restrict__ bbase,
                                                      int* __restrict__ gcur,
                                                      int* __restrict__ barr) {
  __shared__ int lh[NBKT], lres[NBKT], lcur[NBKT];
  int t = threadIdx.x;
  if (t < NBKT) { lh[t] = 0; lcur[t] = 0; }
  __syncthreads();
  int e0 = blockIdx.x * CHUNK;
  int e1 = min(e0 + CHUNK, ET);
  for (int e = e0 + t; e < e1; e += 256) {
    int d = (e < EE) ? ei[EE + e] : e - EE;
    atomicAdd(&lh[d >> 9], 1);
  }
  __syncthreads();
  if (t < NBKT && lh[t]) lres[t] = atomicAdd(&gcur[t], lh[t]);
  __syncthreads();
  for (int e = e0 + t; e < e1; e += 256) {
    int s, d; edge_sd(e, ei, s, d);
    int b = d >> 9;
    int lp = atomicAdd(&lcur[b], 1);
    barr[bbase[b] + lres[b] + lp] = s | ((d & 511) << 17);
  }
}

// ---------- per-bucket: local hist+scan -> rowptr + csr (L2-local writes) ----------
__global__ __launch_bounds__(256) void bucket2csr_kernel(const int* __restrict__ barr,
                                                         const int* __restrict__ bbase,
                                                         int* __restrict__ rowptr,
                                                         int* __restrict__ csr) {
  __shared__ int hist[512];
  __shared__ int sd[256];
  int b = blockIdx.x, t = threadIdx.x;
  int base = bbase[b];
  int cnt = bbase[b + 1] - base;
  hist[t] = 0; hist[t + 256] = 0;
  __syncthreads();
  for (int i = t; i < cnt; i += 256) atomicAdd(&hist[barr[base + i] >> 17], 1);
  __syncthreads();
  int h0 = hist[2 * t], h1 = hist[2 * t + 1], s = h0 + h1;
  sd[t] = s;
  __syncthreads();
  for (int off = 1; off < 256; off <<= 1) {
    int x = sd[t];
    int y = (t >= off) ? sd[t - off] : 0;
    __syncthreads();
    sd[t] = x + y;
    __syncthreads();
  }
  int run = sd[t] - s;   // exclusive base for local dst 2t
  int g = b * 512 + 2 * t;
  if (g < NN) rowptr[g] = base + run;
  if (g + 1 < NN) rowptr[g + 1] = base + run + h0;
  hist[2 * t] = run;
  hist[2 * t + 1] = run + h0;
  __syncthreads();
  for (int i = t; i < cnt; i += 256) {
    int p = barr[base + i];
    int dl = p >> 17;
    int pos = atomicAdd(&hist[dl], 1);
    csr[base + pos] = p & 0x1FFFF;
  }
}

// ---------- layer 1: tiled GEMM 64 nodes x 64 cols, K=128, + att dots ----------
// att dot outputs are PRESCALED by log2(e) so the agg kernels use bare exp2.
__global__ __launch_bounds__(256) void gemm1_kernel(
    const float* __restrict__ x, const float* __restrict__ W,
    const float* __restrict__ att_s, const float* __restrict__ att_d,
    __half* __restrict__ h, float* __restrict__ as, float* __restrict__ ad) {
  __shared__ float sW[FIN * D1];   // [k][col], 32 KB
  __shared__ float sx[64 * FIN];   // swizzled, 32 KB
  int t = threadIdx.x;
  int node0 = blockIdx.x * 64;
  {
    const float4* Wg = (const float4*)W;
    float4* sWq = (float4*)sW;
    for (int i = t; i < FIN * D1 / 4; i += 256) sWq[i] = Wg[i];
  }
  for (int idx = t; idx < 64 * 32; idx += 256) {
    int node = idx >> 5, kq = idx & 31;
    float4 v = make_float4(0.f, 0.f, 0.f, 0.f);
    if (node0 + node < NN) v = ((const float4*)x)[(size_t)(node0 + node) * 32 + kq];
    *(float4*)&sx[node * FIN + ((kq * 4 + 4 * (node >> 2)) & 127)] = v;
  }
  __syncthreads();
  int lane = t & 63, wid = t >> 6;
  int ng = lane & 15, cgl = lane >> 4;
  int col0 = wid * 16 + cgl * 4;
  float acc[4][4];
#pragma unroll
  for (int a = 0; a < 4; ++a)
#pragma unroll
    for (int c = 0; c < 4; ++c) acc[a][c] = 0.f;
  for (int kk = 0; kk < FIN; kk += 4) {
    float4 xv[4], wv[4];
#pragma unroll
    for (int a = 0; a < 4; ++a) {
      int node = ng * 4 + a;
      xv[a] = *(const float4*)&sx[node * FIN + ((kk + 4 * (node >> 2)) & 127)];
    }
#pragma unroll
    for (int b = 0; b < 4; ++b) wv[b] = *(const float4*)&sW[(kk + b) * D1 + col0];
#pragma unroll
    for (int a = 0; a < 4; ++a) {
      acc[a][0] = fmaf(xv[a].x, wv[0].x, acc[a][0]);
      acc[a][1] = fmaf(xv[a].x, wv[0].y, acc[a][1]);
      acc[a][2] = fmaf(xv[a].x, wv[0].z, acc[a][2]);
      acc[a][3] = fmaf(xv[a].x, wv[0].w, acc[a][3]);
      acc[a][0] = fmaf(xv[a].y, wv[1].x, acc[a][0]);
      acc[a][1] = fmaf(xv[a].y, wv[1].y, acc[a][1]);
      acc[a][2] = fmaf(xv[a].y, wv[1].z, acc[a][2]);
      acc[a][3] = fmaf(xv[a].y, wv[1].w, acc[a][3]);
      acc[a][0] = fmaf(xv[a].z, wv[2].x, acc[a][0]);
      acc[a][1] = fmaf(xv[a].z, wv[2].y, acc[a][1]);
      acc[a][2] = fmaf(xv[a].z, wv[2].z, acc[a][2]);
      acc[a][3] = fmaf(xv[a].z, wv[2].w, acc[a][3]);
      acc[a][0] = fmaf(xv[a].w, wv[3].x, acc[a][0]);
      acc[a][1] = fmaf(xv[a].w, wv[3].y, acc[a][1]);
      acc[a][2] = fmaf(xv[a].w, wv[3].z, acc[a][2]);
      acc[a][3] = fmaf(xv[a].w, wv[3].w, acc[a][3]);
    }
  }
#pragma unroll
  for (int a = 0; a < 4; ++a) {
    int node = node0 + ng * 4 + a;
    if (node < NN) {
      __half2 p01 = __floats2half2_rn(acc[a][0], acc[a][1]);
      __half2 p23 = __floats2half2_rn(acc[a][2], acc[a][3]);
      __half2* hp = (__half2*)&h[(size_t)node * D1 + col0];
      hp[0] = p01; hp[1] = p23;
    }
  }
  float aw_s[4], aw_d[4];
#pragma unroll
  for (int j = 0; j < 4; ++j) {
    aw_s[j] = att_s[col0 + j] * LOG2E;
    aw_d[j] = att_d[col0 + j] * LOG2E;
  }
#pragma unroll
  for (int a = 0; a < 4; ++a) {
    float ps = acc[a][0]*aw_s[0] + acc[a][1]*aw_s[1] + acc[a][2]*aw_s[2] + acc[a][3]*aw_s[3];
    float pd = acc[a][0]*aw_d[0] + acc[a][1]*aw_d[1] + acc[a][2]*aw_d[2] + acc[a][3]*aw_d[3];
    ps += __shfl_xor(ps, 16, 64);
    pd += __shfl_xor(pd, 16, 64);
    int node = node0 + ng * 4 + a;
    if ((cgl & 1) == 0 && node < NN) {
      int head = 2 * wid + (cgl >> 1);
      as[node * H1 + head] = ps;
      ad[node * H1 + head] = pd;
    }
  }
}

// ---------- fused aggregation, layer 1: 2 edges/pass via half2 lanes ----------
// lane l covers channels {2*(l&31), 2*(l&31)+1}; lanes 0-31 even-slot edges,
// lanes 32-63 odd-slot edges; final shfl_xor(32) merges the two halves.
__global__ __launch_bounds__(256) void agg1_kernel(
    const int* __restrict__ rowptr, const int* __restrict__ csr,
    const float* __restrict__ as, const float* __restrict__ ad,
    const __half* __restrict__ h, const float* __restrict__ b1,
    float* __restrict__ emb) {
  int node = blockIdx.x * 4 + (threadIdx.x >> 6);
  if (node >= NN) return;
  int lane = threadIdx.x & 63;
  int l31 = lane & 31;
  int hi01 = lane >> 5;            // edge slot parity handled by this lane
  int g = l31 >> 2;                // head of channels 2*l31, 2*l31+1
  const __half2* hb = (const __half2*)h;
  int beg = rowptr[node];
  int end = (node == NN - 1) ? ET : rowptr[node + 1];
  float adv = ad[node * H1 + g];   // prescaled by log2(e)
  float den = 0.f, acc0 = 0.f, acc1 = 0.f;
  for (int i = beg; i < end; i += 64) {
    int nch = min(64, end - i);
    int s64 = csr[i + min(lane, nch - 1)];
    int j = 0;
    for (; j + 8 <= nch; j += 8) {       // 8 edges = 4 pairs, loads batched
      int sj[4]; __half2 hv[4]; float av[4];
#pragma unroll
      for (int p = 0; p < 4; ++p) sj[p] = __shfl(s64, j + 2 * p + hi01, 64);
#pragma unroll
      for (int p = 0; p < 4; ++p) hv[p] = hb[sj[p] * 32 + l31];
#pragma unroll
      for (int p = 0; p < 4; ++p) av[p] = as[sj[p] * H1 + g];
#pragma unroll
      for (int p = 0; p < 4; ++p) {
        float xx = av[p] + adv;
        xx = fmaxf(xx, NEG * xx);
        float ev = exp2f(xx);
        den += ev;
        float2 f = __half22float2(hv[p]);
        acc0 = fmaf(f.x, ev, acc0);
        acc1 = fmaf(f.y, ev, acc1);
      }
    }
    for (; j + 2 <= nch; j += 2) {       // leftover full pairs
      int sj = __shfl(s64, j + hi01, 64);
      __half2 hvv = hb[sj * 32 + l31];
      float xx = as[sj * H1 + g] + adv;
      xx = fmaxf(xx, NEG * xx);
      float ev = exp2f(xx);
      den += ev;
      float2 f = __half22float2(hvv);
      acc0 = fmaf(f.x, ev, acc0);
      acc1 = fmaf(f.y, ev, acc1);
    }
    if (j < nch) {                       // odd tail edge: hi half contributes 0
      int sj = __shfl(s64, j, 64);
      __half2 hvv = hb[sj * 32 + l31];
      float xx = as[sj * H1 + g] + adv;
      xx = fmaxf(xx, NEG * xx);
      float ev = hi01 ? 0.f : exp2f(xx);
      den += ev;
      float2 f = __half22float2(hvv);
      acc0 = fmaf(f.x, ev, acc0);
      acc1 = fmaf(f.y, ev, acc1);
    }
  }
  den  += __shfl_xor(den, 32, 64);
  acc0 += __shfl_xor(acc0, 32, 64);
  acc1 += __shfl_xor(acc1, 32, 64);
  if (lane < 32) {
    float2 bv = *(const float2*)&b1[2 * l31];
    float o0 = acc0 / (den + EPSV) + bv.x;
    float o1 = acc1 / (den + EPSV) + bv.y;
    o0 = o0 > 0.f ? o0 : expm1f(o0);
    o1 = o1 > 0.f ? o1 : expm1f(o1);
    float2 st; st.x = o0; st.y = o1;
    *(float2*)&emb[(size_t)node * D1 + 2 * l31] = st;
  }
}

// ---------- layer 2: tiled GEMM 64 nodes x 64 cols (40 real), K=64, + att dots ----------
__global__ __launch_bounds__(256) void gemm2_kernel(
    const float* __restrict__ emb, const float* __restrict__ W2,
    const float* __restrict__ att_s, const float* __restrict__ att_d,
    __half* __restrict__ h2, float* __restrict__ as, float* __restrict__ ad) {
  __shared__ float sW[D1 * D1];    // [k][col64], cols>=40 zero, 16 KB
  __shared__ float se[64 * D1];    // swizzled, 16 KB
  __shared__ float sred_s[64], sred_d[64];
  int t = threadIdx.x;
  int node0 = blockIdx.x * 64;
  for (int i = t; i < D1 * D1; i += 256) {
    int k = i >> 6, c = i & 63;
    sW[i] = (c < C2) ? W2[k * C2 + c] : 0.f;
  }
  for (int idx = t; idx < 64 * 16; idx += 256) {
    int node = idx >> 4, kq = idx & 15;
    float4 v = make_float4(0.f, 0.f, 0.f, 0.f);
    if (node0 + node < NN) v = ((const float4*)emb)[(size_t)(node0 + node) * 16 + kq];
    *(float4*)&se[node * D1 + ((kq * 4 + 4 * (node >> 2)) & 63)] = v;
  }
  if (t < 64) { sred_s[t] = 0.f; sred_d[t] = 0.f; }
  __syncthreads();
  int lane = t & 63, wid = t >> 6;
  int ng = lane & 15, cgl = lane >> 4;
  int col0 = wid * 16 + cgl * 4;
  float acc[4][4];
#pragma unroll
  for (int a = 0; a < 4; ++a)
#pragma unroll
    for (int c = 0; c < 4; ++c) acc[a][c] = 0.f;
  for (int kk = 0; kk < D1; kk += 4) {
    float4 xv[4], wv[4];
#pragma unroll
    for (int a = 0; a < 4; ++a) {
      int node = ng * 4 + a;
      xv[a] = *(const float4*)&se[node * D1 + ((kk + 4 * (node >> 2)) & 63)];
    }
#pragma unroll
    for (int b = 0; b < 4; ++b) wv[b] = *(const float4*)&sW[(kk + b) * D1 + col0];
#pragma unroll
    for (int a = 0; a < 4; ++a) {
      acc[a][0] = fmaf(xv[a].x, wv[0].x, acc[a][0]);
      acc[a][1] = fmaf(xv[a].x, wv[0].y, acc[a][1]);
      acc[a][2] = fmaf(xv[a].x, wv[0].z, acc[a][2]);
      acc[a][3] = fmaf(xv[a].x, wv[0].w, acc[a][3]);
      acc[a][0] = fmaf(xv[a].y, wv[1].x, acc[a][0]);
      acc[a][1] = fmaf(xv[a].y, wv[1].y, acc[a][1]);
      acc[a][2] = fmaf(xv[a].y, wv[1].z, acc[a][2]);
      acc[a][3] = fmaf(xv[a].y, wv[1].w, acc[a][3]);
      acc[a][0] = fmaf(xv[a].z, wv[2].x, acc[a][0]);
      acc[a][1] = fmaf(xv[a].z, wv[2].y, acc[a][1]);
      acc[a][2] = fmaf(xv[a].z, wv[2].z, acc[a][2]);
      acc[a][3] = fmaf(xv[a].z, wv[2].w, acc[a][3]);
      acc[a][0] = fmaf(xv[a].w, wv[3].x, acc[a][0]);
      acc[a][1] = fmaf(xv[a].w, wv[3].y, acc[a][1]);
      acc[a][2] = fmaf(xv[a].w, wv[3].z, acc[a][2]);
      acc[a][3] = fmaf(xv[a].w, wv[3].w, acc[a][3]);
    }
  }
  if (col0 < C2) {
#pragma unroll
    for (int a = 0; a < 4; ++a) {
      int node = node0 + ng * 4 + a;
      if (node < NN) {
        __half2 p01 = __floats2half2_rn(acc[a][0], acc[a][1]);
        __half2 p23 = __floats2half2_rn(acc[a][2], acc[a][3]);
        __half2* hp = (__half2*)&h2[(size_t)node * C2 + col0];
        hp[0] = p01; hp[1] = p23;
      }
    }
    float aw_s[4], aw_d[4];
#pragma unroll
    for (int j = 0; j < 4; ++j) {
      aw_s[j] = att_s[col0 + j] * LOG2E;
      aw_d[j] = att_d[col0 + j] * LOG2E;
    }
#pragma unroll
    for (int a = 0; a < 4; ++a) {
      float ps = acc[a][0]*aw_s[0] + acc[a][1]*aw_s[1] + acc[a][2]*aw_s[2] + acc[a][3]*aw_s[3];
      float pd = acc[a][0]*aw_d[0] + acc[a][1]*aw_d[1] + acc[a][2]*aw_d[2] + acc[a][3]*aw_d[3];
      atomicAdd(&sred_s[ng * 4 + a], ps);
      atomicAdd(&sred_d[ng * 4 + a], pd);
    }
  }
  __syncthreads();
  if (t < 64 && node0 + t < NN) { as[node0 + t] = sred_s[t]; ad[node0 + t] = sred_d[t]; }
}

// ---------- fused aggregation, layer 2 + bias + log_softmax: 2 edges/pass ----------
__global__ __launch_bounds__(256) void agg2_kernel(
    const int* __restrict__ rowptr, const int* __restrict__ csr,
    const float* __restrict__ as, const float* __restrict__ ad,
    const __half* __restrict__ h2, const float* __restrict__ b2,
    float* __restrict__ out) {
  int node = blockIdx.x * 4 + (threadIdx.x >> 6);
  if (node >= NN) return;
  int lane = threadIdx.x & 63;
  int l31 = lane & 31;
  int hi01 = lane >> 5;
  int lc = min(l31, C2 / 2 - 1);   // 0..19; lanes 20-31 clamp (discarded)
  const __half2* hb = (const __half2*)h2;
  int beg = rowptr[node];
  int end = (node == NN - 1) ? ET : rowptr[node + 1];
  float adv = ad[node];            // prescaled by log2(e)
  float den = 0.f, acc0 = 0.f, acc1 = 0.f;
  for (int i = beg; i < end; i += 64) {
    int nch = min(64, end - i);
    int s64 = csr[i + min(lane, nch - 1)];
    int j = 0;
    for (; j + 8 <= nch; j += 8) {
      int sj[4]; __half2 hv[4]; float av[4];
#pragma unroll
      for (int p = 0; p < 4; ++p) sj[p] = __shfl(s64, j + 2 * p + hi01, 64);
#pragma unroll
      for (int p = 0; p < 4; ++p) hv[p] = hb[sj[p] * 20 + lc];
#pragma unroll
      for (int p = 0; p < 4; ++p) av[p] = as[sj[p]];
#pragma unroll
      for (int p = 0; p < 4; ++p) {
        float xx = av[p] + adv;
        xx = fmaxf(xx, NEG * xx);
        float ev = exp2f(xx);
        den += ev;
        float2 f = __half22float2(hv[p]);
        acc0 = fmaf(f.x, ev, acc0);
        acc1 = fmaf(f.y, ev, acc1);
      }
    }
    for (; j + 2 <= nch; j += 2) {
      int sj = __shfl(s64, j + hi01, 64);
      __half2 hvv = hb[sj * 20 + lc];
      float xx = as[sj] + adv;
      xx = fmaxf(xx, NEG * xx);
      float ev = exp2f(xx);
      den += ev;
      float2 f = __half22float2(hvv);
      acc0 = fmaf(f.x, ev, acc0);
      acc1 = fmaf(f.y, ev, acc1);
    }
    if (j < nch) {
      int sj = __shfl(s64, j, 64);
      __half2 hvv = hb[sj * 20 + lc];
      float xx = as[sj] + adv;
      xx = fmaxf(xx, NEG * xx);
      float ev = hi01 ? 0.f : exp2f(xx);
      den += ev;
      float2 f = __half22float2(hvv);
      acc0 = fmaf(f.x, ev, acc0);
      acc1 = fmaf(f.y, ev, acc1);
    }
  }
  den  += __shfl_xor(den, 32, 64);
  acc0 += __shfl_xor(acc0, 32, 64);
  acc1 += __shfl_xor(acc1, 32, 64);
  float2 bv = *(const float2*)&b2[2 * lc];
  float val0 = acc0 / (den + EPSV) + bv.x;
  float val1 = acc1 / (den + EPSV) + bv.y;
  bool act = (lane < C2 / 2);      // lanes 0..19 carry the 40 unique channels
  float m2 = act ? fmaxf(val0, val1) : -INFINITY;
#pragma unroll
  for (int off = 1; off < 64; off <<= 1) m2 = fmaxf(m2, __shfl_xor(m2, off, 64));
  float ex = act ? (__expf(val0 - m2) + __expf(val1 - m2)) : 0.f;
#pragma unroll
  for (int off = 1; off < 64; off <<= 1) ex += __shfl_xor(ex, off, 64);
  if (act) {
    float lls = m2 + logf(ex);
    float2 st; st.x = val0 - lls; st.y = val1 - lls;
    *(float2*)&out[(size_t)node * C2 + 2 * lane] = st;
  }
}

// ---------- launch ----------
extern "C" void kernel_launch(void* const* d_in, const int* in_sizes, int n_in,
                              void* d_out, int out_size, void* d_ws, size_t ws_size,
                              hipStream_t stream) {
  const float* x    = (const float*)d_in[0];
  const float* W1   = (const float*)d_in[1];
  const float* as1w = (const float*)d_in[2];
  const float* ad1w = (const float*)d_in[3];
  const float* b1   = (const float*)d_in[4];
  const float* W2   = (const float*)d_in[5];
  const float* as2w = (const float*)d_in[6];
  const float* ad2w = (const float*)d_in[7];
  const float* b2   = (const float*)d_in[8];
  const int*   ei   = (const int*)d_in[9];

  float* out   = (float*)d_out;
  float* outls = out;                    // [N,40] log_softmax
  float* emb   = out + (long)NN * C2;    // [N,64] emb

  char* wsb = (char*)d_ws;
  __half* h1   = (__half*)wsb; wsb += sizeof(__half) * (size_t)NN * D1;
  __half* h2   = (__half*)wsb; wsb += sizeof(__half) * ((size_t)NN * C2 + 64);  // +64 pad
  float* asrc1 = (float*)wsb; wsb += sizeof(float) * (size_t)NN * H1;
  float* adst1 = (float*)wsb; wsb += sizeof(float) * (size_t)NN * H1;
  float* asrc2 = (float*)wsb; wsb += sizeof(float) * (size_t)NN;
  float* adst2 = (float*)wsb; wsb += sizeof(float) * (size_t)NN;
  int* rowptr  = (int*)wsb;   wsb += sizeof(int) * (size_t)NN;
  int* ghist   = (int*)wsb;   wsb += sizeof(int) * (NBKT + 4);
  int* bbase   = (int*)wsb;   wsb += sizeof(int) * (NBKT + 4);
  int* gcur    = (int*)wsb;   wsb += sizeof(int) * (NBKT + 4);
  int* barr    = (int*)wsb;   wsb += sizeof(int) * (size_t)ET;
  int* csr     = (int*)wsb;   wsb += sizeof(int) * (size_t)ET;

  // CSR build (bucketed; per call since ws is re-poisoned)
  hipMemsetAsync(ghist, 0, sizeof(int) * (NBKT + 4), stream);
  hipMemsetAsync(gcur, 0, sizeof(int) * (NBKT + 4), stream);
  hist_kernel<<<256, 256, 0, stream>>>(ei, ghist);
  bscan_kernel<<<1, 256, 0, stream>>>(ghist, bbase);
  scatter_kernel<<<NBB, 256, 0, stream>>>(ei, bbase, gcur, barr);
  bucket2csr_kernel<<<NBKT, 256, 0, stream>>>(barr, bbase, rowptr, csr);

  // layer 1
  gemm1_kernel<<<(NN + 63) / 64, 256, 0, stream>>>(x, W1, as1w, ad1w, h1, asrc1, adst1);
  agg1_kernel<<<(NN + 3) / 4, 256, 0, stream>>>(rowptr, csr, asrc1, adst1, h1, b1, emb);

  // layer 2 (gemm + attdot fused)
  gemm2_kernel<<<(NN + 63) / 64, 256, 0, stream>>>(emb, W2, as2w, ad2w, h2, asrc2, adst2);
  agg2_kernel<<<(NN + 3) / 4, 256, 0, stream>>>(rowptr, csr, asrc2, adst2, h2, b2, outls);
}

// Round 2
// 365.397 us; speedup vs baseline: 1.0544x; 1.0052x over previous
//
#include <hip/hip_runtime.h>
#include <hip/hip_fp16.h>
#include <math.h>

#define NN 100000
#define EE 1600000
#define ET (EE + NN)   // 1,700,000 edges incl self-loops
#define FIN 128
#define D1 64          // H1*C1
#define H1 8
#define C1 8
#define C2 40
#define NEG 0.2f
#define EPSV 1e-16f
#define LOG2E 1.4426950408889634f

#define NBKT 196       // buckets of 512 dst: (99999>>9)+1
#define CHUNK 8192     // edges per scatter block
#define NBB ((ET + CHUNK - 1) / CHUNK)

__device__ __forceinline__ void edge_sd(int e, const int* __restrict__ ei, int& s, int& d) {
  if (e < EE) { s = ei[e]; d = ei[EE + e]; }
  else        { s = e - EE; d = s; }
}

// ---------- CSR build: bucket histogram ----------
__global__ __launch_bounds__(256) void hist_kernel(const int* __restrict__ ei,
                                                   int* __restrict__ ghist) {
  __shared__ int lh[NBKT];
  int t = threadIdx.x;
  if (t < NBKT) lh[t] = 0;
  __syncthreads();
  for (int e = blockIdx.x * 256 + t; e < ET; e += gridDim.x * 256) {
    int d = (e < EE) ? ei[EE + e] : e - EE;
    atomicAdd(&lh[d >> 9], 1);
  }
  __syncthreads();
  if (t < NBKT && lh[t]) atomicAdd(&ghist[t], lh[t]);
}

__global__ __launch_bounds__(256) void bscan_kernel(const int* __restrict__ ghist,
                                                    int* __restrict__ bbase) {
  __shared__ int sd[256];
  int t = threadIdx.x;
  int v = (t < NBKT) ? ghist[t] : 0;
  sd[t] = v;
  __syncthreads();
  for (int off = 1; off < 256; off <<= 1) {
    int x = sd[t];
    int y = (t >= off) ? sd[t - off] : 0;
    __syncthreads();
    sd[t] = x + y;
    __syncthreads();
  }
  int excl = sd[t] - v;
  if (t < NBKT) bbase[t] = excl;
  if (t == NBKT - 1) bbase[NBKT] = excl + v;
}

// ---------- scatter edges into bucket array (run-reserved, write-local) ----------
__global__ __launch_bounds__(256) void scatter_kernel(const int* __restrict__ ei,
                                                      const int* __restrict__ bbase,
                                                      int* __restrict__ gcur,
                                                      int* __restrict__ barr) {
  __shared__ int lh[NBKT], lres[NBKT], lcur[NBKT];
  int t = threadIdx.x;
  if (t < NBKT) { lh[t] = 0; lcur[t] = 0; }
  __syncthreads();
  int e0 = blockIdx.x * CHUNK;
  int e1 = min(e0 + CHUNK, ET);
  for (int e = e0 + t; e < e1; e += 256) {
    int d = (e < EE) ? ei[EE + e] : e - EE;
    atomicAdd(&lh[d >> 9], 1);
  }
  __syncthreads();
  if (t < NBKT && lh[t]) lres[t] = atomicAdd(&gcur[t], lh[t]);
  __syncthreads();
  for (int e = e0 + t; e < e1; e += 256) {
    int s, d; edge_sd(e, ei, s, d);
    int b = d >> 9;
    int lp = atomicAdd(&lcur[b], 1);
    barr[bbase[b] + lres[b] + lp] = s | ((d & 511) << 17);
  }
}

// ---------- per-bucket: local hist+scan -> rowptr + csr (L2-local writes) ----------
__global__ __launch_bounds__(256) void bucket2csr_kernel(const int* __restrict__ barr,
                                                         const int* __restrict__ bbase,
                                                         int* __restrict__ rowptr,
                                                         int* __restrict__ csr) {
  __shared__ int hist[512];
  __shared__ int sd[256];
  int b = blockIdx.x, t = threadIdx.x;
  int base = bbase[b];
  int cnt = bbase[b + 1] - base;
  hist[t] = 0; hist[t + 256] = 0;
  __syncthreads();
  for (int i = t; i < cnt; i += 256) atomicAdd(&hist[barr[base + i] >> 17], 1);
  __syncthreads();
  int h0 = hist[2 * t], h1 = hist[2 * t + 1], s = h0 + h1;
  sd[t] = s;
  __syncthreads();
  for (int off = 1; off < 256; off <<= 1) {
    int x = sd[t];
    int y = (t >= off) ? sd[t - off] : 0;
    __syncthreads();
    sd[t] = x + y;
    __syncthreads();
  }
  int run = sd[t] - s;   // exclusive base for local dst 2t
  int g = b * 512 + 2 * t;
  if (g < NN) rowptr[g] = base + run;
  if (g + 1 < NN) rowptr[g + 1] = base + run + h0;
  hist[2 * t] = run;
  hist[2 * t + 1] = run + h0;
  __syncthreads();
  for (int i = t; i < cnt; i += 256) {
    int p = barr[base + i];
    int dl = p >> 17;
    int pos = atomicAdd(&hist[dl], 1);
    csr[base + pos] = p & 0x1FFFF;
  }
}

// ---------- layer 1: tiled GEMM 64 nodes x 64 cols, K=128, + att dots ----------
// att dot outputs are PRESCALED by log2(e) so the agg kernels use bare exp2.
__global__ __launch_bounds__(256) void gemm1_kernel(
    const float* __restrict__ x, const float* __restrict__ W,
    const float* __restrict__ att_s, const float* __restrict__ att_d,
    __half* __restrict__ h, float* __restrict__ as, float* __restrict__ ad) {
  __shared__ float sW[FIN * D1];   // [k][col], 32 KB
  __shared__ float sx[64 * FIN];   // swizzled, 32 KB
  int t = threadIdx.x;
  int node0 = blockIdx.x * 64;
  {
    const float4* Wg = (const float4*)W;
    float4* sWq = (float4*)sW;
    for (int i = t; i < FIN * D1 / 4; i += 256) sWq[i] = Wg[i];
  }
  for (int idx = t; idx < 64 * 32; idx += 256) {
    int node = idx >> 5, kq = idx & 31;
    float4 v = make_float4(0.f, 0.f, 0.f, 0.f);
    if (node0 + node < NN) v = ((const float4*)x)[(size_t)(node0 + node) * 32 + kq];
    *(float4*)&sx[node * FIN + ((kq * 4 + 4 * (node >> 2)) & 127)] = v;
  }
  __syncthreads();
  int lane = t & 63, wid = t >> 6;
  int ng = lane & 15, cgl = lane >> 4;
  int col0 = wid * 16 + cgl * 4;
  float acc[4][4];
#pragma unroll
  for (int a = 0; a < 4; ++a)
#pragma unroll
    for (int c = 0; c < 4; ++c) acc[a][c] = 0.f;
  for (int kk = 0; kk < FIN; kk += 4) {
    float4 xv[4], wv[4];
#pragma unroll
    for (int a = 0; a < 4; ++a) {
      int node = ng * 4 + a;
      xv[a] = *(const float4*)&sx[node * FIN + ((kk + 4 * (node >> 2)) & 127)];
    }
#pragma unroll
    for (int b = 0; b < 4; ++b) wv[b] = *(const float4*)&sW[(kk + b) * D1 + col0];
#pragma unroll
    for (int a = 0; a < 4; ++a) {
      acc[a][0] = fmaf(xv[a].x, wv[0].x, acc[a][0]);
      acc[a][1] = fmaf(xv[a].x, wv[0].y, acc[a][1]);
      acc[a][2] = fmaf(xv[a].x, wv[0].z, acc[a][2]);
      acc[a][3] = fmaf(xv[a].x, wv[0].w, acc[a][3]);
      acc[a][0] = fmaf(xv[a].y, wv[1].x, acc[a][0]);
      acc[a][1] = fmaf(xv[a].y, wv[1].y, acc[a][1]);
      acc[a][2] = fmaf(xv[a].y, wv[1].z, acc[a][2]);
      acc[a][3] = fmaf(xv[a].y, wv[1].w, acc[a][3]);
      acc[a][0] = fmaf(xv[a].z, wv[2].x, acc[a][0]);
      acc[a][1] = fmaf(xv[a].z, wv[2].y, acc[a][1]);
      acc[a][2] = fmaf(xv[a].z, wv[2].z, acc[a][2]);
      acc[a][3] = fmaf(xv[a].z, wv[2].w, acc[a][3]);
      acc[a][0] = fmaf(xv[a].w, wv[3].x, acc[a][0]);
      acc[a][1] = fmaf(xv[a].w, wv[3].y, acc[a][1]);
      acc[a][2] = fmaf(xv[a].w, wv[3].z, acc[a][2]);
      acc[a][3] = fmaf(xv[a].w, wv[3].w, acc[a][3]);
    }
  }
#pragma unroll
  for (int a = 0; a < 4; ++a) {
    int node = node0 + ng * 4 + a;
    if (node < NN) {
      __half2 p01 = __floats2half2_rn(acc[a][0], acc[a][1]);
      __half2 p23 = __floats2half2_rn(acc[a][2], acc[a][3]);
      __half2* hp = (__half2*)&h[(size_t)node * D1 + col0];
      hp[0] = p01; hp[1] = p23;
    }
  }
  float aw_s[4], aw_d[4];
#pragma unroll
  for (int j = 0; j < 4; ++j) {
    aw_s[j] = att_s[col0 + j] * LOG2E;
    aw_d[j] = att_d[col0 + j] * LOG2E;
  }
#pragma unroll
  for (int a = 0; a < 4; ++a) {
    float ps = acc[a][0]*aw_s[0] + acc[a][1]*aw_s[1] + acc[a][2]*aw_s[2] + acc[a][3]*aw_s[3];
    float pd = acc[a][0]*aw_d[0] + acc[a][1]*aw_d[1] + acc[a][2]*aw_d[2] + acc[a][3]*aw_d[3];
    ps += __shfl_xor(ps, 16, 64);
    pd += __shfl_xor(pd, 16, 64);
    int node = node0 + ng * 4 + a;
    if ((cgl & 1) == 0 && node < NN) {
      int head = 2 * wid + (cgl >> 1);
      as[node * H1 + head] = ps;
      ad[node * H1 + head] = pd;
    }
  }
}

// ---------- fused aggregation, layer 1: 4 edges/pass, 4 channels/lane ----------
// quarter q = lane>>4 owns edge j+q; lane r = lane&15 owns channels 4r..4r+3
// (one 8B dwordx2 load). Head g = r>>1. Final shfl_xor(16)+shfl_xor(32) merges.
__global__ __launch_bounds__(256) void agg1_kernel(
    const int* __restrict__ rowptr, const int* __restrict__ csr,
    const float* __restrict__ as, const float* __restrict__ ad,
    const __half* __restrict__ h, const float* __restrict__ b1,
    float* __restrict__ emb) {
  int node = blockIdx.x * 4 + (threadIdx.x >> 6);
  if (node >= NN) return;
  int lane = threadIdx.x & 63;
  int q = lane >> 4;           // edge sub-slot 0..3
  int r = lane & 15;           // channel quad: channels 4r..4r+3
  int g = r >> 1;              // head
  int beg = rowptr[node];
  int end = (node == NN - 1) ? ET : rowptr[node + 1];
  float adv = ad[node * H1 + g];   // prescaled by log2(e)
  float den = 0.f, a0 = 0.f, a1 = 0.f, a2 = 0.f, a3 = 0.f;
  for (int i = beg; i < end; i += 64) {
    int nch = min(64, end - i);
    int s64 = csr[i + min(lane, nch - 1)];
    int j = 0;
    for (; j + 8 <= nch; j += 8) {     // two 4-edge passes, loads batched
      int sj0 = __shfl(s64, j + q, 64);
      int sj1 = __shfl(s64, j + 4 + q, 64);
      uint2 u0 = *(const uint2*)(h + (uint)sj0 * 64u + (r << 2));
      uint2 u1 = *(const uint2*)(h + (uint)sj1 * 64u + (r << 2));
      float av0 = as[(uint)sj0 * 8u + g];
      float av1 = as[(uint)sj1 * 8u + g];
      float x0 = av0 + adv; x0 = fmaxf(x0, NEG * x0); float e0 = exp2f(x0);
      float x1 = av1 + adv; x1 = fmaxf(x1, NEG * x1); float e1 = exp2f(x1);
      den += e0 + e1;
      float2 f;
      f = __half22float2(*(__half2*)&u0.x); a0 = fmaf(f.x, e0, a0); a1 = fmaf(f.y, e0, a1);
      f = __half22float2(*(__half2*)&u0.y); a2 = fmaf(f.x, e0, a2); a3 = fmaf(f.y, e0, a3);
      f = __half22float2(*(__half2*)&u1.x); a0 = fmaf(f.x, e1, a0); a1 = fmaf(f.y, e1, a1);
      f = __half22float2(*(__half2*)&u1.y); a2 = fmaf(f.x, e1, a2); a3 = fmaf(f.y, e1, a3);
    }
    for (; j + 4 <= nch; j += 4) {     // single full 4-edge pass
      int sj = __shfl(s64, j + q, 64);
      uint2 u = *(const uint2*)(h + (uint)sj * 64u + (r << 2));
      float av = as[(uint)sj * 8u + g];
      float xx = av + adv; xx = fmaxf(xx, NEG * xx);
      float e = exp2f(xx);
      den += e;
      float2 f;
      f = __half22float2(*(__half2*)&u.x); a0 = fmaf(f.x, e, a0); a1 = fmaf(f.y, e, a1);
      f = __half22float2(*(__half2*)&u.y); a2 = fmaf(f.x, e, a2); a3 = fmaf(f.y, e, a3);
    }
    if (j < nch) {                     // masked tail pass (1..3 edges)
      int idx = j + q;
      int sj = __shfl(s64, min(idx, nch - 1), 64);
      uint2 u = *(const uint2*)(h + (uint)sj * 64u + (r << 2));
      float av = as[(uint)sj * 8u + g];
      float xx = av + adv; xx = fmaxf(xx, NEG * xx);
      float e = (idx < nch) ? exp2f(xx) : 0.f;
      den += e;
      float2 f;
      f = __half22float2(*(__half2*)&u.x); a0 = fmaf(f.x, e, a0); a1 = fmaf(f.y, e, a1);
      f = __half22float2(*(__half2*)&u.y); a2 = fmaf(f.x, e, a2); a3 = fmaf(f.y, e, a3);
    }
  }
  den += __shfl_xor(den, 16, 64); den += __shfl_xor(den, 32, 64);
  a0 += __shfl_xor(a0, 16, 64); a0 += __shfl_xor(a0, 32, 64);
  a1 += __shfl_xor(a1, 16, 64); a1 += __shfl_xor(a1, 32, 64);
  a2 += __shfl_xor(a2, 16, 64); a2 += __shfl_xor(a2, 32, 64);
  a3 += __shfl_xor(a3, 16, 64); a3 += __shfl_xor(a3, 32, 64);
  if (lane < 16) {
    float4 bv = ((const float4*)b1)[r];
    float inv = 1.0f / (den + EPSV);
    float o0 = fmaf(a0, inv, bv.x);
    float o1 = fmaf(a1, inv, bv.y);
    float o2 = fmaf(a2, inv, bv.z);
    float o3 = fmaf(a3, inv, bv.w);
    o0 = o0 > 0.f ? o0 : expm1f(o0);
    o1 = o1 > 0.f ? o1 : expm1f(o1);
    o2 = o2 > 0.f ? o2 : expm1f(o2);
    o3 = o3 > 0.f ? o3 : expm1f(o3);
    float4 st; st.x = o0; st.y = o1; st.z = o2; st.w = o3;
    *(float4*)&emb[(size_t)node * D1 + (r << 2)] = st;
  }
}

// ---------- layer 2: tiled GEMM 64 nodes x 64 cols (40 real), K=64, + att dots ----------
__global__ __launch_bounds__(256) void gemm2_kernel(
    const float* __restrict__ emb, const float* __restrict__ W2,
    const float* __restrict__ att_s, const float* __restrict__ att_d,
    __half* __restrict__ h2, float* __restrict__ as, float* __restrict__ ad) {
  __shared__ float sW[D1 * D1];    // [k][col64], cols>=40 zero, 16 KB
  __shared__ float se[64 * D1];    // swizzled, 16 KB
  __shared__ float sred_s[64], sred_d[64];
  int t = threadIdx.x;
  int node0 = blockIdx.x * 64;
  for (int i = t; i < D1 * D1; i += 256) {
    int k = i >> 6, c = i & 63;
    sW[i] = (c < C2) ? W2[k * C2 + c] : 0.f;
  }
  for (int idx = t; idx < 64 * 16; idx += 256) {
    int node = idx >> 4, kq = idx & 15;
    float4 v = make_float4(0.f, 0.f, 0.f, 0.f);
    if (node0 + node < NN) v = ((const float4*)emb)[(size_t)(node0 + node) * 16 + kq];
    *(float4*)&se[node * D1 + ((kq * 4 + 4 * (node >> 2)) & 63)] = v;
  }
  if (t < 64) { sred_s[t] = 0.f; sred_d[t] = 0.f; }
  __syncthreads();
  int lane = t & 63, wid = t >> 6;
  int ng = lane & 15, cgl = lane >> 4;
  int col0 = wid * 16 + cgl * 4;
  float acc[4][4];
#pragma unroll
  for (int a = 0; a < 4; ++a)
#pragma unroll
    for (int c = 0; c < 4; ++c) acc[a][c] = 0.f;
  for (int kk = 0; kk < D1; kk += 4) {
    float4 xv[4], wv[4];
#pragma unroll
    for (int a = 0; a < 4; ++a) {
      int node = ng * 4 + a;
      xv[a] = *(const float4*)&se[node * D1 + ((kk + 4 * (node >> 2)) & 63)];
    }
#pragma unroll
    for (int b = 0; b < 4; ++b) wv[b] = *(const float4*)&sW[(kk + b) * D1 + col0];
#pragma unroll
    for (int a = 0; a < 4; ++a) {
      acc[a][0] = fmaf(xv[a].x, wv[0].x, acc[a][0]);
      acc[a][1] = fmaf(xv[a].x, wv[0].y, acc[a][1]);
      acc[a][2] = fmaf(xv[a].x, wv[0].z, acc[a][2]);
      acc[a][3] = fmaf(xv[a].x, wv[0].w, acc[a][3]);
      acc[a][0] = fmaf(xv[a].y, wv[1].x, acc[a][0]);
      acc[a][1] = fmaf(xv[a].y, wv[1].y, acc[a][1]);
      acc[a][2] = fmaf(xv[a].y, wv[1].z, acc[a][2]);
      acc[a][3] = fmaf(xv[a].y, wv[1].w, acc[a][3]);
      acc[a][0] = fmaf(xv[a].z, wv[2].x, acc[a][0]);
      acc[a][1] = fmaf(xv[a].z, wv[2].y, acc[a][1]);
      acc[a][2] = fmaf(xv[a].z, wv[2].z, acc[a][2]);
      acc[a][3] = fmaf(xv[a].z, wv[2].w, acc[a][3]);
      acc[a][0] = fmaf(xv[a].w, wv[3].x, acc[a][0]);
      acc[a][1] = fmaf(xv[a].w, wv[3].y, acc[a][1]);
      acc[a][2] = fmaf(xv[a].w, wv[3].z, acc[a][2]);
      acc[a][3] = fmaf(xv[a].w, wv[3].w, acc[a][3]);
    }
  }
  if (col0 < C2) {
#pragma unroll
    for (int a = 0; a < 4; ++a) {
      int node = node0 + ng * 4 + a;
      if (node < NN) {
        __half2 p01 = __floats2half2_rn(acc[a][0], acc[a][1]);
        __half2 p23 = __floats2half2_rn(acc[a][2], acc[a][3]);
        __half2* hp = (__half2*)&h2[(size_t)node * C2 + col0];
        hp[0] = p01; hp[1] = p23;
      }
    }
    float aw_s[4], aw_d[4];
#pragma unroll
    for (int j = 0; j < 4; ++j) {
      aw_s[j] = att_s[col0 + j] * LOG2E;
      aw_d[j] = att_d[col0 + j] * LOG2E;
    }
#pragma unroll
    for (int a = 0; a < 4; ++a) {
      float ps = acc[a][0]*aw_s[0] + acc[a][1]*aw_s[1] + acc[a][2]*aw_s[2] + acc[a][3]*aw_s[3];
      float pd = acc[a][0]*aw_d[0] + acc[a][1]*aw_d[1] + acc[a][2]*aw_d[2] + acc[a][3]*aw_d[3];
      atomicAdd(&sred_s[ng * 4 + a], ps);
      atomicAdd(&sred_d[ng * 4 + a], pd);
    }
  }
  __syncthreads();
  if (t < 64 && node0 + t < NN) { as[node0 + t] = sred_s[t]; ad[node0 + t] = sred_d[t]; }
}

// ---------- fused aggregation, layer 2 + bias + log_softmax: 4 edges/pass ----------
// quarter q owns edge j+q; lane r = lane&15 owns channels 4r..4r+3 (r<10 real).
__global__ __launch_bounds__(256) void agg2_kernel(
    const int* __restrict__ rowptr, const int* __restrict__ csr,
    const float* __restrict__ as, const float* __restrict__ ad,
    const __half* __restrict__ h2, const float* __restrict__ b2,
    float* __restrict__ out) {
  int node = blockIdx.x * 4 + (threadIdx.x >> 6);
  if (node >= NN) return;
  int lane = threadIdx.x & 63;
  int q = lane >> 4;
  int r = lane & 15;
  int rc = min(r, 9);              // channel quad clamp (lanes r>=10 duplicate, masked)
  int beg = rowptr[node];
  int end = (node == NN - 1) ? ET : rowptr[node + 1];
  float adv = ad[node];            // prescaled by log2(e)
  float den = 0.f, a0 = 0.f, a1 = 0.f, a2 = 0.f, a3 = 0.f;
  for (int i = beg; i < end; i += 64) {
    int nch = min(64, end - i);
    int s64 = csr[i + min(lane, nch - 1)];
    int j = 0;
    for (; j + 8 <= nch; j += 8) {
      int sj0 = __shfl(s64, j + q, 64);
      int sj1 = __shfl(s64, j + 4 + q, 64);
      uint2 u0 = *(const uint2*)(h2 + (uint)sj0 * 40u + (rc << 2));
      uint2 u1 = *(const uint2*)(h2 + (uint)sj1 * 40u + (rc << 2));
      float av0 = as[sj0];
      float av1 = as[sj1];
      float x0 = av0 + adv; x0 = fmaxf(x0, NEG * x0); float e0 = exp2f(x0);
      float x1 = av1 + adv; x1 = fmaxf(x1, NEG * x1); float e1 = exp2f(x1);
      den += e0 + e1;
      float2 f;
      f = __half22float2(*(__half2*)&u0.x); a0 = fmaf(f.x, e0, a0); a1 = fmaf(f.y, e0, a1);
      f = __half22float2(*(__half2*)&u0.y); a2 = fmaf(f.x, e0, a2); a3 = fmaf(f.y, e0, a3);
      f = __half22float2(*(__half2*)&u1.x); a0 = fmaf(f.x, e1, a0); a1 = fmaf(f.y, e1, a1);
      f = __half22float2(*(__half2*)&u1.y); a2 = fmaf(f.x, e1, a2); a3 = fmaf(f.y, e1, a3);
    }
    for (; j + 4 <= nch; j += 4) {
      int sj = __shfl(s64, j + q, 64);
      uint2 u = *(const uint2*)(h2 + (uint)sj * 40u + (rc << 2));
      float av = as[sj];
      float xx = av + adv; xx = fmaxf(xx, NEG * xx);
      float e = exp2f(xx);
      den += e;
      float2 f;
      f = __half22float2(*(__half2*)&u.x); a0 = fmaf(f.x, e, a0); a1 = fmaf(f.y, e, a1);
      f = __half22float2(*(__half2*)&u.y); a2 = fmaf(f.x, e, a2); a3 = fmaf(f.y, e, a3);
    }
    if (j < nch) {
      int idx = j + q;
      int sj = __shfl(s64, min(idx, nch - 1), 64);
      uint2 u = *(const uint2*)(h2 + (uint)sj * 40u + (rc << 2));
      float av = as[sj];
      float xx = av + adv; xx = fmaxf(xx, NEG * xx);
      float e = (idx < nch) ? exp2f(xx) : 0.f;
      den += e;
      float2 f;
      f = __half22float2(*(__half2*)&u.x); a0 = fmaf(f.x, e, a0); a1 = fmaf(f.y, e, a1);
      f = __half22float2(*(__half2*)&u.y); a2 = fmaf(f.x, e, a2); a3 = fmaf(f.y, e, a3);
    }
  }
  den += __shfl_xor(den, 16, 64); den += __shfl_xor(den, 32, 64);
  a0 += __shfl_xor(a0, 16, 64); a0 += __shfl_xor(a0, 32, 64);
  a1 += __shfl_xor(a1, 16, 64); a1 += __shfl_xor(a1, 32, 64);
  a2 += __shfl_xor(a2, 16, 64); a2 += __shfl_xor(a2, 32, 64);
  a3 += __shfl_xor(a3, 16, 64); a3 += __shfl_xor(a3, 32, 64);
  float4 bv = ((const float4*)b2)[rc];
  float inv = 1.0f / (den + EPSV);
  float v0 = fmaf(a0, inv, bv.x);
  float v1 = fmaf(a1, inv, bv.y);
  float v2 = fmaf(a2, inv, bv.z);
  float v3 = fmaf(a3, inv, bv.w);
  bool act = (r < 10);
  float m = act ? fmaxf(fmaxf(v0, v1), fmaxf(v2, v3)) : -INFINITY;
#pragma unroll
  for (int off = 1; off < 16; off <<= 1) m = fmaxf(m, __shfl_xor(m, off, 64));
  float ex = act ? (__expf(v0 - m) + __expf(v1 - m) + __expf(v2 - m) + __expf(v3 - m)) : 0.f;
#pragma unroll
  for (int off = 1; off < 16; off <<= 1) ex += __shfl_xor(ex, off, 64);
  if (lane < 10) {                 // one quarter writes, lanes 0..9 = 40 channels
    float lls = m + __logf(ex);
    float4 st; st.x = v0 - lls; st.y = v1 - lls; st.z = v2 - lls; st.w = v3 - lls;
    *(float4*)&out[(size_t)node * C2 + (r << 2)] = st;
  }
}

// ---------- launch ----------
extern "C" void kernel_launch(void* const* d_in, const int* in_sizes, int n_in,
                              void* d_out, int out_size, void* d_ws, size_t ws_size,
                              hipStream_t stream) {
  const float* x    = (const float*)d_in[0];
  const float* W1   = (const float*)d_in[1];
  const float* as1w = (const float*)d_in[2];
  const float* ad1w = (const float*)d_in[3];
  const float* b1   = (const float*)d_in[4];
  const float* W2   = (const float*)d_in[5];
  const float* as2w = (const float*)d_in[6];
  const float* ad2w = (const float*)d_in[7];
  const float* b2   = (const float*)d_in[8];
  const int*   ei   = (const int*)d_in[9];

  float* out   = (float*)d_out;
  float* outls = out;                    // [N,40] log_softmax
  float* emb   = out + (long)NN * C2;    // [N,64] emb

  char* wsb = (char*)d_ws;
  __half* h1   = (__half*)wsb; wsb += sizeof(__half) * (size_t)NN * D1;
  __half* h2   = (__half*)wsb; wsb += sizeof(__half) * ((size_t)NN * C2 + 64);  // +64 pad
  float* asrc1 = (float*)wsb; wsb += sizeof(float) * (size_t)NN * H1;
  float* adst1 = (float*)wsb; wsb += sizeof(float) * (size_t)NN * H1;
  float* asrc2 = (float*)wsb; wsb += sizeof(float) * (size_t)NN;
  float* adst2 = (float*)wsb; wsb += sizeof(float) * (size_t)NN;
  int* rowptr  = (int*)wsb;   wsb += sizeof(int) * (size_t)NN;
  int* ghist   = (int*)wsb;   wsb += sizeof(int) * (NBKT + 4);
  int* bbase   = (int*)wsb;   wsb += sizeof(int) * (NBKT + 4);
  int* gcur    = (int*)wsb;   wsb += sizeof(int) * (NBKT + 4);
  int* barr    = (int*)wsb;   wsb += sizeof(int) * (size_t)ET;
  int* csr     = (int*)wsb;   wsb += sizeof(int) * (size_t)ET;

  // CSR build (bucketed; per call since ws is re-poisoned)
  hipMemsetAsync(ghist, 0, sizeof(int) * (NBKT + 4), stream);
  hipMemsetAsync(gcur, 0, sizeof(int) * (NBKT + 4), stream);
  hist_kernel<<<256, 256, 0, stream>>>(ei, ghist);
  bscan_kernel<<<1, 256, 0, stream>>>(ghist, bbase);
  scatter_kernel<<<NBB, 256, 0, stream>>>(ei, bbase, gcur, barr);
  bucket2csr_kernel<<<NBKT, 256, 0, stream>>>(barr, bbase, rowptr, csr);

  // layer 1
  gemm1_kernel<<<(NN + 63) / 64, 256, 0, stream>>>(x, W1, as1w, ad1w, h1, asrc1, adst1);
  agg1_kernel<<<(NN + 3) / 4, 256, 0, stream>>>(rowptr, csr, asrc1, adst1, h1, b1, emb);

  // layer 2 (gemm + attdot fused)
  gemm2_kernel<<<(NN + 63) / 64, 256, 0, stream>>>(emb, W2, as2w, ad2w, h2, asrc2, adst2);
  agg2_kernel<<<(NN + 3) / 4, 256, 0, stream>>>(rowptr, csr, asrc2, adst2, h2, b2, outls);
}

// Round 3
// 331.333 us; speedup vs baseline: 1.1628x; 1.1028x over previous
//
#include <hip/hip_runtime.h>
#include <hip/hip_fp16.h>
#include <math.h>

#define NN 100000
#define EE 1600000
#define ET (EE + NN)   // 1,700,000 edges incl self-loops
#define FIN 128
#define D1 64          // H1*C1
#define H1 8
#define C1 8
#define C2 40
#define NEG 0.2f
#define EPSV 1e-16f
#define LOG2E 1.4426950408889634f

#define NBKT 196       // buckets of 512 dst: (99999>>9)+1
#define BCAP 10240     // fixed bucket capacity (max count ~9200)
#define CHUNK 8192     // edges per scatter block
#define NBB ((ET + CHUNK - 1) / CHUNK)
#define H2S 48         // h2 row stride in halfs (40 ch + as@40 + pad)

__device__ __forceinline__ void edge_sd(int e, const int* __restrict__ ei, int& s, int& d) {
  if (e < EE) { s = ei[e]; d = ei[EE + e]; }
  else        { s = e - EE; d = s; }
}

// ---------- scatter edges into fixed-capacity buckets (direct reserve) ----------
__global__ __launch_bounds__(256) void scatter_kernel(const int* __restrict__ ei,
                                                      int* __restrict__ gcur,
                                                      int* __restrict__ ecsr) {
  __shared__ int lh[NBKT], lres[NBKT], lcur[NBKT];
  int t = threadIdx.x;
  if (t < NBKT) { lh[t] = 0; lcur[t] = 0; }
  __syncthreads();
  int e0 = blockIdx.x * CHUNK;
  int e1 = min(e0 + CHUNK, ET);
  for (int e = e0 + t; e < e1; e += 256) {
    int d = (e < EE) ? ei[EE + e] : e - EE;
    atomicAdd(&lh[d >> 9], 1);
  }
  __syncthreads();
  if (t < NBKT && lh[t]) lres[t] = atomicAdd(&gcur[t], lh[t]);
  __syncthreads();
  for (int e = e0 + t; e < e1; e += 256) {
    int s, d; edge_sd(e, ei, s, d);
    int b = d >> 9;
    int lp = atomicAdd(&lcur[b], 1);
    ecsr[b * BCAP + lres[b] + lp] = s | ((d & 511) << 17);
  }
}

// ---------- per-bucket: LDS-staged in-place sort -> rowrng(beg,end) + csr ----------
__global__ __launch_bounds__(256) void bucket2csr_kernel(const int* __restrict__ gcur,
                                                         int2* __restrict__ rowrng,
                                                         int* __restrict__ ecsr) {
  __shared__ int ebuf[BCAP];     // 40 KB
  __shared__ int hist[512];
  __shared__ int sd[256];
  int b = blockIdx.x, t = threadIdx.x;
  int base = b * BCAP;
  int cnt = gcur[b];
  hist[t] = 0; hist[t + 256] = 0;
  __syncthreads();
  for (int i = t; i < cnt; i += 256) {
    int p = ecsr[base + i];
    ebuf[i] = p;
    atomicAdd(&hist[p >> 17], 1);
  }
  __syncthreads();
  int h0 = hist[2 * t], h1 = hist[2 * t + 1], s = h0 + h1;
  sd[t] = s;
  __syncthreads();
  for (int off = 1; off < 256; off <<= 1) {
    int x = sd[t];
    int y = (t >= off) ? sd[t - off] : 0;
    __syncthreads();
    sd[t] = x + y;
    __syncthreads();
  }
  int run = sd[t] - s;   // exclusive base for local dst 2t
  int g = b * 512 + 2 * t;
  if (g < NN)     rowrng[g]     = make_int2(base + run,      base + run + h0);
  if (g + 1 < NN) rowrng[g + 1] = make_int2(base + run + h0, base + run + h0 + h1);
  hist[2 * t] = run;
  hist[2 * t + 1] = run + h0;
  __syncthreads();
  for (int i = t; i < cnt; i += 256) {
    int p = ebuf[i];
    int pos = atomicAdd(&hist[p >> 17], 1);
    ecsr[base + pos] = p & 0x1FFFF;
  }
}

// ---------- layer 1: tiled GEMM 64 nodes x 64 cols, K=128, + att dots ----------
// att dot outputs are PRESCALED by log2(e) so the agg kernels use bare exp2.
__global__ __launch_bounds__(256) void gemm1_kernel(
    const float* __restrict__ x, const float* __restrict__ W,
    const float* __restrict__ att_s, const float* __restrict__ att_d,
    __half* __restrict__ h, float* __restrict__ as, float* __restrict__ ad) {
  __shared__ float sW[FIN * D1];   // [k][col], 32 KB
  __shared__ float sx[64 * FIN];   // swizzled, 32 KB
  int t = threadIdx.x;
  int node0 = blockIdx.x * 64;
  {
    const float4* Wg = (const float4*)W;
    float4* sWq = (float4*)sW;
    for (int i = t; i < FIN * D1 / 4; i += 256) sWq[i] = Wg[i];
  }
  for (int idx = t; idx < 64 * 32; idx += 256) {
    int node = idx >> 5, kq = idx & 31;
    float4 v = make_float4(0.f, 0.f, 0.f, 0.f);
    if (node0 + node < NN) v = ((const float4*)x)[(size_t)(node0 + node) * 32 + kq];
    *(float4*)&sx[node * FIN + ((kq * 4 + 4 * (node >> 2)) & 127)] = v;
  }
  __syncthreads();
  int lane = t & 63, wid = t >> 6;
  int ng = lane & 15, cgl = lane >> 4;
  int col0 = wid * 16 + cgl * 4;
  float acc[4][4];
#pragma unroll
  for (int a = 0; a < 4; ++a)
#pragma unroll
    for (int c = 0; c < 4; ++c) acc[a][c] = 0.f;
  for (int kk = 0; kk < FIN; kk += 4) {
    float4 xv[4], wv[4];
#pragma unroll
    for (int a = 0; a < 4; ++a) {
      int node = ng * 4 + a;
      xv[a] = *(const float4*)&sx[node * FIN + ((kk + 4 * (node >> 2)) & 127)];
    }
#pragma unroll
    for (int b = 0; b < 4; ++b) wv[b] = *(const float4*)&sW[(kk + b) * D1 + col0];
#pragma unroll
    for (int a = 0; a < 4; ++a) {
      acc[a][0] = fmaf(xv[a].x, wv[0].x, acc[a][0]);
      acc[a][1] = fmaf(xv[a].x, wv[0].y, acc[a][1]);
      acc[a][2] = fmaf(xv[a].x, wv[0].z, acc[a][2]);
      acc[a][3] = fmaf(xv[a].x, wv[0].w, acc[a][3]);
      acc[a][0] = fmaf(xv[a].y, wv[1].x, acc[a][0]);
      acc[a][1] = fmaf(xv[a].y, wv[1].y, acc[a][1]);
      acc[a][2] = fmaf(xv[a].y, wv[1].z, acc[a][2]);
      acc[a][3] = fmaf(xv[a].y, wv[1].w, acc[a][3]);
      acc[a][0] = fmaf(xv[a].z, wv[2].x, acc[a][0]);
      acc[a][1] = fmaf(xv[a].z, wv[2].y, acc[a][1]);
      acc[a][2] = fmaf(xv[a].z, wv[2].z, acc[a][2]);
      acc[a][3] = fmaf(xv[a].z, wv[2].w, acc[a][3]);
      acc[a][0] = fmaf(xv[a].w, wv[3].x, acc[a][0]);
      acc[a][1] = fmaf(xv[a].w, wv[3].y, acc[a][1]);
      acc[a][2] = fmaf(xv[a].w, wv[3].z, acc[a][2]);
      acc[a][3] = fmaf(xv[a].w, wv[3].w, acc[a][3]);
    }
  }
#pragma unroll
  for (int a = 0; a < 4; ++a) {
    int node = node0 + ng * 4 + a;
    if (node < NN) {
      __half2 p01 = __floats2half2_rn(acc[a][0], acc[a][1]);
      __half2 p23 = __floats2half2_rn(acc[a][2], acc[a][3]);
      __half2* hp = (__half2*)&h[(size_t)node * D1 + col0];
      hp[0] = p01; hp[1] = p23;
    }
  }
  float aw_s[4], aw_d[4];
#pragma unroll
  for (int j = 0; j < 4; ++j) {
    aw_s[j] = att_s[col0 + j] * LOG2E;
    aw_d[j] = att_d[col0 + j] * LOG2E;
  }
#pragma unroll
  for (int a = 0; a < 4; ++a) {
    float ps = acc[a][0]*aw_s[0] + acc[a][1]*aw_s[1] + acc[a][2]*aw_s[2] + acc[a][3]*aw_s[3];
    float pd = acc[a][0]*aw_d[0] + acc[a][1]*aw_d[1] + acc[a][2]*aw_d[2] + acc[a][3]*aw_d[3];
    ps += __shfl_xor(ps, 16, 64);
    pd += __shfl_xor(pd, 16, 64);
    int node = node0 + ng * 4 + a;
    if ((cgl & 1) == 0 && node < NN) {
      int head = 2 * wid + (cgl >> 1);
      as[node * H1 + head] = ps;
      ad[node * H1 + head] = pd;
    }
  }
}

// ---------- fused aggregation, layer 1: octet layout, 16 edges/iter ----------
// lane = o*8+k: octet o owns edge j+o (and j+8+o); lane k owns channels 8k..8k+7
// (one dwordx4) and head k. csr loaded directly (no shfl staging). Cross-octet
// reduce via shfl_xor(8,16,32).
__global__ __launch_bounds__(256) void agg1_kernel(
    const int2* __restrict__ rowrng, const int* __restrict__ csr,
    const float* __restrict__ as, const float* __restrict__ ad,
    const __half* __restrict__ h, const float* __restrict__ b1,
    float* __restrict__ emb) {
  int node = blockIdx.x * 4 + (threadIdx.x >> 6);
  if (node >= NN) return;
  int lane = threadIdx.x & 63;
  int o = lane >> 3;           // edge slot 0..7
  int k = lane & 7;            // channel group / head
  int2 rr = rowrng[node];
  int beg = rr.x, end = rr.y, mend = end - 1;
  float adv = ad[node * H1 + k];   // prescaled by log2(e)
  float den = 0.f;
  float a0=0.f,a1=0.f,a2=0.f,a3=0.f,a4=0.f,a5=0.f,a6=0.f,a7=0.f;
  int sjA = csr[min(beg + o, mend)];
  int sjB = csr[min(beg + 8 + o, mend)];
  for (int j = beg; j < end; j += 16) {
    int sjA2 = csr[min(j + 16 + o, mend)];
    int sjB2 = csr[min(j + 24 + o, mend)];
    uint4 uA = *(const uint4*)(h + (size_t)(uint)sjA * 64u + (k << 3));
    uint4 uB = *(const uint4*)(h + (size_t)(uint)sjB * 64u + (k << 3));
    float avA = as[(uint)sjA * 8u + k];
    float avB = as[(uint)sjB * 8u + k];
    float xA = avA + adv; xA = fmaxf(xA, NEG * xA);
    float xB = avB + adv; xB = fmaxf(xB, NEG * xB);
    float eA = (j + o < end) ? exp2f(xA) : 0.f;
    float eB = (j + 8 + o < end) ? exp2f(xB) : 0.f;
    den += eA + eB;
    float2 f;
    f = __half22float2(*(__half2*)&uA.x); a0 = fmaf(f.x, eA, a0); a1 = fmaf(f.y, eA, a1);
    f = __half22float2(*(__half2*)&uA.y); a2 = fmaf(f.x, eA, a2); a3 = fmaf(f.y, eA, a3);
    f = __half22float2(*(__half2*)&uA.z); a4 = fmaf(f.x, eA, a4); a5 = fmaf(f.y, eA, a5);
    f = __half22float2(*(__half2*)&uA.w); a6 = fmaf(f.x, eA, a6); a7 = fmaf(f.y, eA, a7);
    f = __half22float2(*(__half2*)&uB.x); a0 = fmaf(f.x, eB, a0); a1 = fmaf(f.y, eB, a1);
    f = __half22float2(*(__half2*)&uB.y); a2 = fmaf(f.x, eB, a2); a3 = fmaf(f.y, eB, a3);
    f = __half22float2(*(__half2*)&uB.z); a4 = fmaf(f.x, eB, a4); a5 = fmaf(f.y, eB, a5);
    f = __half22float2(*(__half2*)&uB.w); a6 = fmaf(f.x, eB, a6); a7 = fmaf(f.y, eB, a7);
    sjA = sjA2; sjB = sjB2;
  }
#pragma unroll
  for (int off = 8; off < 64; off <<= 1) {
    den += __shfl_xor(den, off, 64);
    a0 += __shfl_xor(a0, off, 64); a1 += __shfl_xor(a1, off, 64);
    a2 += __shfl_xor(a2, off, 64); a3 += __shfl_xor(a3, off, 64);
    a4 += __shfl_xor(a4, off, 64); a5 += __shfl_xor(a5, off, 64);
    a6 += __shfl_xor(a6, off, 64); a7 += __shfl_xor(a7, off, 64);
  }
  if (lane < 8) {              // o==0, k=lane
    float4 bv0 = ((const float4*)b1)[2 * k];
    float4 bv1 = ((const float4*)b1)[2 * k + 1];
    float inv = 1.0f / (den + EPSV);
    float v0 = fmaf(a0, inv, bv0.x), v1 = fmaf(a1, inv, bv0.y);
    float v2 = fmaf(a2, inv, bv0.z), v3 = fmaf(a3, inv, bv0.w);
    float v4 = fmaf(a4, inv, bv1.x), v5 = fmaf(a5, inv, bv1.y);
    float v6 = fmaf(a6, inv, bv1.z), v7 = fmaf(a7, inv, bv1.w);
    v0 = v0 > 0.f ? v0 : expm1f(v0); v1 = v1 > 0.f ? v1 : expm1f(v1);
    v2 = v2 > 0.f ? v2 : expm1f(v2); v3 = v3 > 0.f ? v3 : expm1f(v3);
    v4 = v4 > 0.f ? v4 : expm1f(v4); v5 = v5 > 0.f ? v5 : expm1f(v5);
    v6 = v6 > 0.f ? v6 : expm1f(v6); v7 = v7 > 0.f ? v7 : expm1f(v7);
    float4 s0; s0.x = v0; s0.y = v1; s0.z = v2; s0.w = v3;
    float4 s1; s1.x = v4; s1.y = v5; s1.z = v6; s1.w = v7;
    float* ep = emb + (size_t)node * D1 + (k << 3);
    ((float4*)ep)[0] = s0; ((float4*)ep)[1] = s1;
  }
}

// ---------- layer 2: tiled GEMM, h2 stride 48 with inline as-half at [40] ----------
__global__ __launch_bounds__(256) void gemm2_kernel(
    const float* __restrict__ emb, const float* __restrict__ W2,
    const float* __restrict__ att_s, const float* __restrict__ att_d,
    __half* __restrict__ h2, float* __restrict__ ad) {
  __shared__ float sW[D1 * D1];    // [k][col64], cols>=40 zero, 16 KB
  __shared__ float se[64 * D1];    // swizzled, 16 KB
  __shared__ float sred_s[64], sred_d[64];
  int t = threadIdx.x;
  int node0 = blockIdx.x * 64;
  for (int i = t; i < D1 * D1; i += 256) {
    int k = i >> 6, c = i & 63;
    sW[i] = (c < C2) ? W2[k * C2 + c] : 0.f;
  }
  for (int idx = t; idx < 64 * 16; idx += 256) {
    int node = idx >> 4, kq = idx & 15;
    float4 v = make_float4(0.f, 0.f, 0.f, 0.f);
    if (node0 + node < NN) v = ((const float4*)emb)[(size_t)(node0 + node) * 16 + kq];
    *(float4*)&se[node * D1 + ((kq * 4 + 4 * (node >> 2)) & 63)] = v;
  }
  if (t < 64) { sred_s[t] = 0.f; sred_d[t] = 0.f; }
  __syncthreads();
  int lane = t & 63, wid = t >> 6;
  int ng = lane & 15, cgl = lane >> 4;
  int col0 = wid * 16 + cgl * 4;
  float acc[4][4];
#pragma unroll
  for (int a = 0; a < 4; ++a)
#pragma unroll
    for (int c = 0; c < 4; ++c) acc[a][c] = 0.f;
  for (int kk = 0; kk < D1; kk += 4) {
    float4 xv[4], wv[4];
#pragma unroll
    for (int a = 0; a < 4; ++a) {
      int node = ng * 4 + a;
      xv[a] = *(const float4*)&se[node * D1 + ((kk + 4 * (node >> 2)) & 63)];
    }
#pragma unroll
    for (int b = 0; b < 4; ++b) wv[b] = *(const float4*)&sW[(kk + b) * D1 + col0];
#pragma unroll
    for (int a = 0; a < 4; ++a) {
      acc[a][0] = fmaf(xv[a].x, wv[0].x, acc[a][0]);
      acc[a][1] = fmaf(xv[a].x, wv[0].y, acc[a][1]);
      acc[a][2] = fmaf(xv[a].x, wv[0].z, acc[a][2]);
      acc[a][3] = fmaf(xv[a].x, wv[0].w, acc[a][3]);
      acc[a][0] = fmaf(xv[a].y, wv[1].x, acc[a][0]);
      acc[a][1] = fmaf(xv[a].y, wv[1].y, acc[a][1]);
      acc[a][2] = fmaf(xv[a].y, wv[1].z, acc[a][2]);
      acc[a][3] = fmaf(xv[a].y, wv[1].w, acc[a][3]);
      acc[a][0] = fmaf(xv[a].z, wv[2].x, acc[a][0]);
      acc[a][1] = fmaf(xv[a].z, wv[2].y, acc[a][1]);
      acc[a][2] = fmaf(xv[a].z, wv[2].z, acc[a][2]);
      acc[a][3] = fmaf(xv[a].z, wv[2].w, acc[a][3]);
      acc[a][0] = fmaf(xv[a].w, wv[3].x, acc[a][0]);
      acc[a][1] = fmaf(xv[a].w, wv[3].y, acc[a][1]);
      acc[a][2] = fmaf(xv[a].w, wv[3].z, acc[a][2]);
      acc[a][3] = fmaf(xv[a].w, wv[3].w, acc[a][3]);
    }
  }
  if (col0 < C2) {
#pragma unroll
    for (int a = 0; a < 4; ++a) {
      int node = node0 + ng * 4 + a;
      if (node < NN) {
        __half2 p01 = __floats2half2_rn(acc[a][0], acc[a][1]);
        __half2 p23 = __floats2half2_rn(acc[a][2], acc[a][3]);
        __half2* hp = (__half2*)&h2[(size_t)node * H2S + col0];
        hp[0] = p01; hp[1] = p23;
      }
    }
    float aw_s[4], aw_d[4];
#pragma unroll
    for (int j = 0; j < 4; ++j) {
      aw_s[j] = att_s[col0 + j] * LOG2E;
      aw_d[j] = att_d[col0 + j] * LOG2E;
    }
#pragma unroll
    for (int a = 0; a < 4; ++a) {
      float ps = acc[a][0]*aw_s[0] + acc[a][1]*aw_s[1] + acc[a][2]*aw_s[2] + acc[a][3]*aw_s[3];
      float pd = acc[a][0]*aw_d[0] + acc[a][1]*aw_d[1] + acc[a][2]*aw_d[2] + acc[a][3]*aw_d[3];
      atomicAdd(&sred_s[ng * 4 + a], ps);
      atomicAdd(&sred_d[ng * 4 + a], pd);
    }
  }
  __syncthreads();
  if (t < 64 && node0 + t < NN) {
    h2[(size_t)(node0 + t) * H2S + 40] = __float2half(sred_s[t]);   // inline as
    ad[node0 + t] = sred_d[t];
  }
}

// ---------- fused aggregation, layer 2 + bias + log_softmax: octet layout ----------
// octet o owns edge j+o (and j+8+o); lane k owns channels 8k..8k+7 (k<5 real,
// k>=5 clamped dup, discarded). as read inline from h2 row (same cachelines).
__global__ __launch_bounds__(256) void agg2_kernel(
    const int2* __restrict__ rowrng, const int* __restrict__ csr,
    const float* __restrict__ ad, const __half* __restrict__ h2,
    const float* __restrict__ b2, float* __restrict__ out) {
  int node = blockIdx.x * 4 + (threadIdx.x >> 6);
  if (node >= NN) return;
  int lane = threadIdx.x & 63;
  int o = lane >> 3;
  int k = lane & 7;
  int kc = min(k, 4);
  int2 rr = rowrng[node];
  int beg = rr.x, end = rr.y, mend = end - 1;
  float adv = ad[node];            // prescaled by log2(e)
  float den = 0.f;
  float a0=0.f,a1=0.f,a2=0.f,a3=0.f,a4=0.f,a5=0.f,a6=0.f,a7=0.f;
  int sjA = csr[min(beg + o, mend)];
  int sjB = csr[min(beg + 8 + o, mend)];
  for (int j = beg; j < end; j += 16) {
    int sjA2 = csr[min(j + 16 + o, mend)];
    int sjB2 = csr[min(j + 24 + o, mend)];
    const __half* rA = h2 + (size_t)(uint)sjA * H2S;
    const __half* rB = h2 + (size_t)(uint)sjB * H2S;
    uint4 uA = *(const uint4*)(rA + (kc << 3));
    uint4 uB = *(const uint4*)(rB + (kc << 3));
    float avA = __half2float(rA[40]);
    float avB = __half2float(rB[40]);
    float xA = avA + adv; xA = fmaxf(xA, NEG * xA);
    float xB = avB + adv; xB = fmaxf(xB, NEG * xB);
    float eA = (j + o < end) ? exp2f(xA) : 0.f;
    float eB = (j + 8 + o < end) ? exp2f(xB) : 0.f;
    den += eA + eB;
    float2 f;
    f = __half22float2(*(__half2*)&uA.x); a0 = fmaf(f.x, eA, a0); a1 = fmaf(f.y, eA, a1);
    f = __half22float2(*(__half2*)&uA.y); a2 = fmaf(f.x, eA, a2); a3 = fmaf(f.y, eA, a3);
    f = __half22float2(*(__half2*)&uA.z); a4 = fmaf(f.x, eA, a4); a5 = fmaf(f.y, eA, a5);
    f = __half22float2(*(__half2*)&uA.w); a6 = fmaf(f.x, eA, a6); a7 = fmaf(f.y, eA, a7);
    f = __half22float2(*(__half2*)&uB.x); a0 = fmaf(f.x, eB, a0); a1 = fmaf(f.y, eB, a1);
    f = __half22float2(*(__half2*)&uB.y); a2 = fmaf(f.x, eB, a2); a3 = fmaf(f.y, eB, a3);
    f = __half22float2(*(__half2*)&uB.z); a4 = fmaf(f.x, eB, a4); a5 = fmaf(f.y, eB, a5);
    f = __half22float2(*(__half2*)&uB.w); a6 = fmaf(f.x, eB, a6); a7 = fmaf(f.y, eB, a7);
    sjA = sjA2; sjB = sjB2;
  }
#pragma unroll
  for (int off = 8; off < 64; off <<= 1) {
    den += __shfl_xor(den, off, 64);
    a0 += __shfl_xor(a0, off, 64); a1 += __shfl_xor(a1, off, 64);
    a2 += __shfl_xor(a2, off, 64); a3 += __shfl_xor(a3, off, 64);
    a4 += __shfl_xor(a4, off, 64); a5 += __shfl_xor(a5, off, 64);
    a6 += __shfl_xor(a6, off, 64); a7 += __shfl_xor(a7, off, 64);
  }
  // epilogue on lanes o==0 (all octets compute identically; only o==0 stores)
  float4 bv0 = ((const float4*)b2)[2 * kc];
  float4 bv1 = ((const float4*)b2)[2 * kc + 1];
  float inv = 1.0f / (den + EPSV);
  float v0 = fmaf(a0, inv, bv0.x), v1 = fmaf(a1, inv, bv0.y);
  float v2 = fmaf(a2, inv, bv0.z), v3 = fmaf(a3, inv, bv0.w);
  float v4 = fmaf(a4, inv, bv1.x), v5 = fmaf(a5, inv, bv1.y);
  float v6 = fmaf(a6, inv, bv1.z), v7 = fmaf(a7, inv, bv1.w);
  bool act = (k < 5);
  float m = fmaxf(fmaxf(fmaxf(v0, v1), fmaxf(v2, v3)),
                  fmaxf(fmaxf(v4, v5), fmaxf(v6, v7)));   // k>=5 dup of k=4: harmless
#pragma unroll
  for (int off = 1; off < 8; off <<= 1) m = fmaxf(m, __shfl_xor(m, off, 64));
  float ex = act ? (__expf(v0 - m) + __expf(v1 - m) + __expf(v2 - m) + __expf(v3 - m) +
                    __expf(v4 - m) + __expf(v5 - m) + __expf(v6 - m) + __expf(v7 - m)) : 0.f;
#pragma unroll
  for (int off = 1; off < 8; off <<= 1) ex += __shfl_xor(ex, off, 64);
  if (lane < 5) {                  // o==0 && k<5: 5 lanes x 8 ch = 40
    float lls = m + logf(ex);
    float4 s0; s0.x = v0 - lls; s0.y = v1 - lls; s0.z = v2 - lls; s0.w = v3 - lls;
    float4 s1; s1.x = v4 - lls; s1.y = v5 - lls; s1.z = v6 - lls; s1.w = v7 - lls;
    float* op = out + (size_t)node * C2 + (k << 3);
    ((float4*)op)[0] = s0; ((float4*)op)[1] = s1;
  }
}

// ---------- launch ----------
extern "C" void kernel_launch(void* const* d_in, const int* in_sizes, int n_in,
                              void* d_out, int out_size, void* d_ws, size_t ws_size,
                              hipStream_t stream) {
  const float* x    = (const float*)d_in[0];
  const float* W1   = (const float*)d_in[1];
  const float* as1w = (const float*)d_in[2];
  const float* ad1w = (const float*)d_in[3];
  const float* b1   = (const float*)d_in[4];
  const float* W2   = (const float*)d_in[5];
  const float* as2w = (const float*)d_in[6];
  const float* ad2w = (const float*)d_in[7];
  const float* b2   = (const float*)d_in[8];
  const int*   ei   = (const int*)d_in[9];

  float* out   = (float*)d_out;
  float* outls = out;                    // [N,40] log_softmax
  float* emb   = out + (long)NN * C2;    // [N,64] emb

  char* wsb = (char*)d_ws;
  __half* h1   = (__half*)wsb; wsb += sizeof(__half) * (size_t)NN * D1;
  __half* h2   = (__half*)wsb; wsb += sizeof(__half) * ((size_t)NN * H2S + 64);  // +pad
  float* asrc1 = (float*)wsb; wsb += sizeof(float) * (size_t)NN * H1;
  float* adst1 = (float*)wsb; wsb += sizeof(float) * (size_t)NN * H1;
  float* adst2 = (float*)wsb; wsb += sizeof(float) * (size_t)NN;
  int2* rowrng = (int2*)wsb;  wsb += sizeof(int2) * (size_t)NN;
  int* gcur    = (int*)wsb;   wsb += sizeof(int) * (NBKT + 4);
  int* ecsr    = (int*)wsb;   wsb += sizeof(int) * (size_t)NBKT * BCAP;

  // CSR build (bucketed, 2 kernels; per call since ws is re-poisoned)
  hipMemsetAsync(gcur, 0, sizeof(int) * (NBKT + 4), stream);
  scatter_kernel<<<NBB, 256, 0, stream>>>(ei, gcur, ecsr);
  bucket2csr_kernel<<<NBKT, 256, 0, stream>>>(gcur, rowrng, ecsr);

  // layer 1
  gemm1_kernel<<<(NN + 63) / 64, 256, 0, stream>>>(x, W1, as1w, ad1w, h1, asrc1, adst1);
  agg1_kernel<<<(NN + 3) / 4, 256, 0, stream>>>(rowrng, ecsr, asrc1, adst1, h1, b1, emb);

  // layer 2 (gemm + attdot fused, as2 inlined into h2 rows)
  gemm2_kernel<<<(NN + 63) / 64, 256, 0, stream>>>(emb, W2, as2w, ad2w, h2, adst2);
  agg2_kernel<<<(NN + 3) / 4, 256, 0, stream>>>(rowrng, ecsr, adst2, h2, b2, outls);
}

// Round 4
// 316.818 us; speedup vs baseline: 1.2161x; 1.0458x over previous
//
#include <hip/hip_runtime.h>
#include <hip/hip_fp16.h>
#include <math.h>

#define NN 100000
#define EE 1600000
#define ET (EE + NN)   // 1,700,000 edges incl self-loops
#define FIN 128
#define D1 64          // H1*C1
#define H1 8
#define C1 8
#define C2 40
#define NEG 0.2f
#define EPSV 1e-16f
#define LOG2E 1.4426950408889634f

#define NBKT 196       // buckets of 512 dst: (99999>>9)+1
#define BCAP 10240     // fixed bucket capacity (max count ~9200)
#define CHUNK 8192     // edges per scatter block
#define NBB ((ET + CHUNK - 1) / CHUNK)
#define H2S 48         // h2 row stride in halfs (40 ch + as@40 + pad)

__device__ __forceinline__ void edge_sd(int e, const int* __restrict__ ei, int& s, int& d) {
  if (e < EE) { s = ei[e]; d = ei[EE + e]; }
  else        { s = e - EE; d = s; }
}

// ---------- scatter edges into fixed-capacity buckets (direct reserve) ----------
__global__ __launch_bounds__(256) void scatter_kernel(const int* __restrict__ ei,
                                                      int* __restrict__ gcur,
                                                      int* __restrict__ ecsr) {
  __shared__ int lh[NBKT], lres[NBKT], lcur[NBKT];
  int t = threadIdx.x;
  if (t < NBKT) { lh[t] = 0; lcur[t] = 0; }
  __syncthreads();
  int e0 = blockIdx.x * CHUNK;
  int e1 = min(e0 + CHUNK, ET);
  for (int e = e0 + t; e < e1; e += 256) {
    int d = (e < EE) ? ei[EE + e] : e - EE;
    atomicAdd(&lh[d >> 9], 1);
  }
  __syncthreads();
  if (t < NBKT && lh[t]) lres[t] = atomicAdd(&gcur[t], lh[t]);
  __syncthreads();
  for (int e = e0 + t; e < e1; e += 256) {
    int s, d; edge_sd(e, ei, s, d);
    int b = d >> 9;
    int lp = atomicAdd(&lcur[b], 1);
    ecsr[b * BCAP + lres[b] + lp] = s | ((d & 511) << 17);
  }
}

// ---------- per-bucket: LDS-staged in-place sort -> rowrng(beg,end) + csr ----------
__global__ __launch_bounds__(256) void bucket2csr_kernel(const int* __restrict__ gcur,
                                                         int2* __restrict__ rowrng,
                                                         int* __restrict__ ecsr) {
  __shared__ int ebuf[BCAP];     // 40 KB
  __shared__ int hist[512];
  __shared__ int sd[256];
  int b = blockIdx.x, t = threadIdx.x;
  int base = b * BCAP;
  int cnt = gcur[b];
  hist[t] = 0; hist[t + 256] = 0;
  __syncthreads();
  for (int i = t; i < cnt; i += 256) {
    int p = ecsr[base + i];
    ebuf[i] = p;
    atomicAdd(&hist[p >> 17], 1);
  }
  __syncthreads();
  int h0 = hist[2 * t], h1 = hist[2 * t + 1], s = h0 + h1;
  sd[t] = s;
  __syncthreads();
  for (int off = 1; off < 256; off <<= 1) {
    int x = sd[t];
    int y = (t >= off) ? sd[t - off] : 0;
    __syncthreads();
    sd[t] = x + y;
    __syncthreads();
  }
  int run = sd[t] - s;   // exclusive base for local dst 2t
  int g = b * 512 + 2 * t;
  if (g < NN)     rowrng[g]     = make_int2(base + run,      base + run + h0);
  if (g + 1 < NN) rowrng[g + 1] = make_int2(base + run + h0, base + run + h0 + h1);
  hist[2 * t] = run;
  hist[2 * t + 1] = run + h0;
  __syncthreads();
  for (int i = t; i < cnt; i += 256) {
    int p = ebuf[i];
    int pos = atomicAdd(&hist[p >> 17], 1);
    ecsr[base + pos] = p & 0x1FFFF;
  }
}

// ---------- layer 1: tiled GEMM 64 nodes x 64 cols, K=128, + att dots ----------
// att dot outputs are PRESCALED by log2(e) so the agg kernels use bare exp2.
__global__ __launch_bounds__(256) void gemm1_kernel(
    const float* __restrict__ x, const float* __restrict__ W,
    const float* __restrict__ att_s, const float* __restrict__ att_d,
    __half* __restrict__ h, float* __restrict__ as, float* __restrict__ ad) {
  __shared__ float sW[FIN * D1];   // [k][col], 32 KB
  __shared__ float sx[64 * FIN];   // swizzled, 32 KB
  int t = threadIdx.x;
  int node0 = blockIdx.x * 64;
  {
    const float4* Wg = (const float4*)W;
    float4* sWq = (float4*)sW;
    for (int i = t; i < FIN * D1 / 4; i += 256) sWq[i] = Wg[i];
  }
  for (int idx = t; idx < 64 * 32; idx += 256) {
    int node = idx >> 5, kq = idx & 31;
    float4 v = make_float4(0.f, 0.f, 0.f, 0.f);
    if (node0 + node < NN) v = ((const float4*)x)[(size_t)(node0 + node) * 32 + kq];
    *(float4*)&sx[node * FIN + ((kq * 4 + 4 * (node >> 2)) & 127)] = v;
  }
  __syncthreads();
  int lane = t & 63, wid = t >> 6;
  int ng = lane & 15, cgl = lane >> 4;
  int col0 = wid * 16 + cgl * 4;
  float acc[4][4];
#pragma unroll
  for (int a = 0; a < 4; ++a)
#pragma unroll
    for (int c = 0; c < 4; ++c) acc[a][c] = 0.f;
  for (int kk = 0; kk < FIN; kk += 4) {
    float4 xv[4], wv[4];
#pragma unroll
    for (int a = 0; a < 4; ++a) {
      int node = ng * 4 + a;
      xv[a] = *(const float4*)&sx[node * FIN + ((kk + 4 * (node >> 2)) & 127)];
    }
#pragma unroll
    for (int b = 0; b < 4; ++b) wv[b] = *(const float4*)&sW[(kk + b) * D1 + col0];
#pragma unroll
    for (int a = 0; a < 4; ++a) {
      acc[a][0] = fmaf(xv[a].x, wv[0].x, acc[a][0]);
      acc[a][1] = fmaf(xv[a].x, wv[0].y, acc[a][1]);
      acc[a][2] = fmaf(xv[a].x, wv[0].z, acc[a][2]);
      acc[a][3] = fmaf(xv[a].x, wv[0].w, acc[a][3]);
      acc[a][0] = fmaf(xv[a].y, wv[1].x, acc[a][0]);
      acc[a][1] = fmaf(xv[a].y, wv[1].y, acc[a][1]);
      acc[a][2] = fmaf(xv[a].y, wv[1].z, acc[a][2]);
      acc[a][3] = fmaf(xv[a].y, wv[1].w, acc[a][3]);
      acc[a][0] = fmaf(xv[a].z, wv[2].x, acc[a][0]);
      acc[a][1] = fmaf(xv[a].z, wv[2].y, acc[a][1]);
      acc[a][2] = fmaf(xv[a].z, wv[2].z, acc[a][2]);
      acc[a][3] = fmaf(xv[a].z, wv[2].w, acc[a][3]);
      acc[a][0] = fmaf(xv[a].w, wv[3].x, acc[a][0]);
      acc[a][1] = fmaf(xv[a].w, wv[3].y, acc[a][1]);
      acc[a][2] = fmaf(xv[a].w, wv[3].z, acc[a][2]);
      acc[a][3] = fmaf(xv[a].w, wv[3].w, acc[a][3]);
    }
  }
#pragma unroll
  for (int a = 0; a < 4; ++a) {
    int node = node0 + ng * 4 + a;
    if (node < NN) {
      __half2 p01 = __floats2half2_rn(acc[a][0], acc[a][1]);
      __half2 p23 = __floats2half2_rn(acc[a][2], acc[a][3]);
      __half2* hp = (__half2*)&h[(size_t)node * D1 + col0];
      hp[0] = p01; hp[1] = p23;
    }
  }
  float aw_s[4], aw_d[4];
#pragma unroll
  for (int j = 0; j < 4; ++j) {
    aw_s[j] = att_s[col0 + j] * LOG2E;
    aw_d[j] = att_d[col0 + j] * LOG2E;
  }
#pragma unroll
  for (int a = 0; a < 4; ++a) {
    float ps = acc[a][0]*aw_s[0] + acc[a][1]*aw_s[1] + acc[a][2]*aw_s[2] + acc[a][3]*aw_s[3];
    float pd = acc[a][0]*aw_d[0] + acc[a][1]*aw_d[1] + acc[a][2]*aw_d[2] + acc[a][3]*aw_d[3];
    ps += __shfl_xor(ps, 16, 64);
    pd += __shfl_xor(pd, 16, 64);
    int node = node0 + ng * 4 + a;
    if ((cgl & 1) == 0 && node < NN) {
      int head = 2 * wid + (cgl >> 1);
      as[node * H1 + head] = ps;
      ad[node * H1 + head] = pd;
    }
  }
}

// ---------- fused aggregation, layer 1: OCTET-PER-NODE ----------
// 8 nodes/wave, 32/block. Lane k of octet o owns channels 8k..8k+7 = head k
// of node node0+o. den/acc lane-private -> NO cross-lane reduction. csr ids
// pre-loaded 8-wide per octet (coalesced), broadcast via intra-octet shfl.
__global__ __launch_bounds__(256) void agg1_kernel(
    const int2* __restrict__ rowrng, const int* __restrict__ csr,
    const float* __restrict__ as, const float* __restrict__ ad,
    const __half* __restrict__ h, const float* __restrict__ b1,
    float* __restrict__ emb) {
  int t = threadIdx.x;
  int lane = t & 63;
  int o = lane >> 3;          // octet = node slot in wave
  int k = lane & 7;           // channel group / head
  int ob = lane & 56;         // o*8 (shfl base)
  int node = blockIdx.x * 32 + (t >> 6) * 8 + o;   // NN%32==0, no guard
  int2 rr = rowrng[node];
  int beg = rr.x, deg = rr.y - rr.x, degm1 = deg - 1;
  float adv = ad[node * H1 + k];   // prescaled by log2(e)
  float den = 0.f;
  float a0=0.f,a1=0.f,a2=0.f,a3=0.f,a4=0.f,a5=0.f,a6=0.f,a7=0.f;
  int sreg = csr[beg + min(k, degm1)];   // 8 edge ids per octet, lane k holds id i+k
  for (int i = 0; i < deg; i += 8) {
    int snext = csr[beg + min(i + 8 + k, degm1)];
#pragma unroll
    for (int r = 0; r < 8; ++r) {
      int sj = __shfl(sreg, ob + r, 64);
      uint4 u = *(const uint4*)(h + ((size_t)(uint)sj << 6) + (k << 3));
      float av = as[(uint)sj * 8u + k];
      float xx = av + adv; xx = fmaxf(xx, NEG * xx);
      float e = (i + r < deg) ? exp2f(xx) : 0.f;
      den += e;
      float2 f;
      f = __half22float2(*(__half2*)&u.x); a0 = fmaf(f.x, e, a0); a1 = fmaf(f.y, e, a1);
      f = __half22float2(*(__half2*)&u.y); a2 = fmaf(f.x, e, a2); a3 = fmaf(f.y, e, a3);
      f = __half22float2(*(__half2*)&u.z); a4 = fmaf(f.x, e, a4); a5 = fmaf(f.y, e, a5);
      f = __half22float2(*(__half2*)&u.w); a6 = fmaf(f.x, e, a6); a7 = fmaf(f.y, e, a7);
    }
    sreg = snext;
  }
  float4 bv0 = ((const float4*)b1)[2 * k];
  float4 bv1 = ((const float4*)b1)[2 * k + 1];
  float inv = 1.0f / (den + EPSV);
  float v0 = fmaf(a0, inv, bv0.x), v1 = fmaf(a1, inv, bv0.y);
  float v2 = fmaf(a2, inv, bv0.z), v3 = fmaf(a3, inv, bv0.w);
  float v4 = fmaf(a4, inv, bv1.x), v5 = fmaf(a5, inv, bv1.y);
  float v6 = fmaf(a6, inv, bv1.z), v7 = fmaf(a7, inv, bv1.w);
  v0 = v0 > 0.f ? v0 : expm1f(v0); v1 = v1 > 0.f ? v1 : expm1f(v1);
  v2 = v2 > 0.f ? v2 : expm1f(v2); v3 = v3 > 0.f ? v3 : expm1f(v3);
  v4 = v4 > 0.f ? v4 : expm1f(v4); v5 = v5 > 0.f ? v5 : expm1f(v5);
  v6 = v6 > 0.f ? v6 : expm1f(v6); v7 = v7 > 0.f ? v7 : expm1f(v7);
  float4 s0; s0.x = v0; s0.y = v1; s0.z = v2; s0.w = v3;
  float4 s1; s1.x = v4; s1.y = v5; s1.z = v6; s1.w = v7;
  float* ep = emb + (size_t)node * D1 + (k << 3);
  ((float4*)ep)[0] = s0; ((float4*)ep)[1] = s1;
}

// ---------- layer 2: tiled GEMM, h2 stride 48 with inline as-half at [40] ----------
__global__ __launch_bounds__(256) void gemm2_kernel(
    const float* __restrict__ emb, const float* __restrict__ W2,
    const float* __restrict__ att_s, const float* __restrict__ att_d,
    __half* __restrict__ h2, float* __restrict__ ad) {
  __shared__ float sW[D1 * D1];    // [k][col64], cols>=40 zero, 16 KB
  __shared__ float se[64 * D1];    // swizzled, 16 KB
  __shared__ float sred_s[64], sred_d[64];
  int t = threadIdx.x;
  int node0 = blockIdx.x * 64;
  for (int i = t; i < D1 * D1; i += 256) {
    int k = i >> 6, c = i & 63;
    sW[i] = (c < C2) ? W2[k * C2 + c] : 0.f;
  }
  for (int idx = t; idx < 64 * 16; idx += 256) {
    int node = idx >> 4, kq = idx & 15;
    float4 v = make_float4(0.f, 0.f, 0.f, 0.f);
    if (node0 + node < NN) v = ((const float4*)emb)[(size_t)(node0 + node) * 16 + kq];
    *(float4*)&se[node * D1 + ((kq * 4 + 4 * (node >> 2)) & 63)] = v;
  }
  if (t < 64) { sred_s[t] = 0.f; sred_d[t] = 0.f; }
  __syncthreads();
  int lane = t & 63, wid = t >> 6;
  int ng = lane & 15, cgl = lane >> 4;
  int col0 = wid * 16 + cgl * 4;
  float acc[4][4];
#pragma unroll
  for (int a = 0; a < 4; ++a)
#pragma unroll
    for (int c = 0; c < 4; ++c) acc[a][c] = 0.f;
  for (int kk = 0; kk < D1; kk += 4) {
    float4 xv[4], wv[4];
#pragma unroll
    for (int a = 0; a < 4; ++a) {
      int node = ng * 4 + a;
      xv[a] = *(const float4*)&se[node * D1 + ((kk + 4 * (node >> 2)) & 63)];
    }
#pragma unroll
    for (int b = 0; b < 4; ++b) wv[b] = *(const float4*)&sW[(kk + b) * D1 + col0];
#pragma unroll
    for (int a = 0; a < 4; ++a) {
      acc[a][0] = fmaf(xv[a].x, wv[0].x, acc[a][0]);
      acc[a][1] = fmaf(xv[a].x, wv[0].y, acc[a][1]);
      acc[a][2] = fmaf(xv[a].x, wv[0].z, acc[a][2]);
      acc[a][3] = fmaf(xv[a].x, wv[0].w, acc[a][3]);
      acc[a][0] = fmaf(xv[a].y, wv[1].x, acc[a][0]);
      acc[a][1] = fmaf(xv[a].y, wv[1].y, acc[a][1]);
      acc[a][2] = fmaf(xv[a].y, wv[1].z, acc[a][2]);
      acc[a][3] = fmaf(xv[a].y, wv[1].w, acc[a][3]);
      acc[a][0] = fmaf(xv[a].z, wv[2].x, acc[a][0]);
      acc[a][1] = fmaf(xv[a].z, wv[2].y, acc[a][1]);
      acc[a][2] = fmaf(xv[a].z, wv[2].z, acc[a][2]);
      acc[a][3] = fmaf(xv[a].z, wv[2].w, acc[a][3]);
      acc[a][0] = fmaf(xv[a].w, wv[3].x, acc[a][0]);
      acc[a][1] = fmaf(xv[a].w, wv[3].y, acc[a][1]);
      acc[a][2] = fmaf(xv[a].w, wv[3].z, acc[a][2]);
      acc[a][3] = fmaf(xv[a].w, wv[3].w, acc[a][3]);
    }
  }
  if (col0 < C2) {
#pragma unroll
    for (int a = 0; a < 4; ++a) {
      int node = node0 + ng * 4 + a;
      if (node < NN) {
        __half2 p01 = __floats2half2_rn(acc[a][0], acc[a][1]);
        __half2 p23 = __floats2half2_rn(acc[a][2], acc[a][3]);
        __half2* hp = (__half2*)&h2[(size_t)node * H2S + col0];
        hp[0] = p01; hp[1] = p23;
      }
    }
    float aw_s[4], aw_d[4];
#pragma unroll
    for (int j = 0; j < 4; ++j) {
      aw_s[j] = att_s[col0 + j] * LOG2E;
      aw_d[j] = att_d[col0 + j] * LOG2E;
    }
#pragma unroll
    for (int a = 0; a < 4; ++a) {
      float ps = acc[a][0]*aw_s[0] + acc[a][1]*aw_s[1] + acc[a][2]*aw_s[2] + acc[a][3]*aw_s[3];
      float pd = acc[a][0]*aw_d[0] + acc[a][1]*aw_d[1] + acc[a][2]*aw_d[2] + acc[a][3]*aw_d[3];
      atomicAdd(&sred_s[ng * 4 + a], ps);
      atomicAdd(&sred_d[ng * 4 + a], pd);
    }
  }
  __syncthreads();
  if (t < 64 && node0 + t < NN) {
    h2[(size_t)(node0 + t) * H2S + 40] = __float2half(sred_s[t]);   // inline as
    ad[node0 + t] = sred_d[t];
  }
}

// ---------- fused aggregation, layer 2 + log_softmax: OCTET-PER-NODE ----------
// Lane k<5 owns channels 8k..8k+7 (k>=5 clamped dup, masked). av inline from
// h2 row (same cachelines). Log-softmax = 3-level intra-octet butterfly.
__global__ __launch_bounds__(256) void agg2_kernel(
    const int2* __restrict__ rowrng, const int* __restrict__ csr,
    const float* __restrict__ ad, const __half* __restrict__ h2,
    const float* __restrict__ b2, float* __restrict__ out) {
  int t = threadIdx.x;
  int lane = t & 63;
  int o = lane >> 3;
  int k = lane & 7;
  int ob = lane & 56;
  int kc = min(k, 4);
  int node = blockIdx.x * 32 + (t >> 6) * 8 + o;
  int2 rr = rowrng[node];
  int beg = rr.x, deg = rr.y - rr.x, degm1 = deg - 1;
  float adv = ad[node];            // prescaled by log2(e)
  float den = 0.f;
  float a0=0.f,a1=0.f,a2=0.f,a3=0.f,a4=0.f,a5=0.f,a6=0.f,a7=0.f;
  int sreg = csr[beg + min(k, degm1)];
  for (int i = 0; i < deg; i += 8) {
    int snext = csr[beg + min(i + 8 + k, degm1)];
#pragma unroll
    for (int r = 0; r < 8; ++r) {
      int sj = __shfl(sreg, ob + r, 64);
      const __half* rA = h2 + (size_t)(uint)sj * H2S;
      uint4 u = *(const uint4*)(rA + (kc << 3));
      float av = __half2float(rA[40]);
      float xx = av + adv; xx = fmaxf(xx, NEG * xx);
      float e = (i + r < deg) ? exp2f(xx) : 0.f;
      den += e;
      float2 f;
      f = __half22float2(*(__half2*)&u.x); a0 = fmaf(f.x, e, a0); a1 = fmaf(f.y, e, a1);
      f = __half22float2(*(__half2*)&u.y); a2 = fmaf(f.x, e, a2); a3 = fmaf(f.y, e, a3);
      f = __half22float2(*(__half2*)&u.z); a4 = fmaf(f.x, e, a4); a5 = fmaf(f.y, e, a5);
      f = __half22float2(*(__half2*)&u.w); a6 = fmaf(f.x, e, a6); a7 = fmaf(f.y, e, a7);
    }
    sreg = snext;
  }
  float4 bv0 = ((const float4*)b2)[2 * kc];
  float4 bv1 = ((const float4*)b2)[2 * kc + 1];
  float inv = 1.0f / (den + EPSV);
  float v0 = fmaf(a0, inv, bv0.x), v1 = fmaf(a1, inv, bv0.y);
  float v2 = fmaf(a2, inv, bv0.z), v3 = fmaf(a3, inv, bv0.w);
  float v4 = fmaf(a4, inv, bv1.x), v5 = fmaf(a5, inv, bv1.y);
  float v6 = fmaf(a6, inv, bv1.z), v7 = fmaf(a7, inv, bv1.w);
  bool act = (k < 5);
  float m = act ? fmaxf(fmaxf(fmaxf(v0, v1), fmaxf(v2, v3)),
                        fmaxf(fmaxf(v4, v5), fmaxf(v6, v7))) : -INFINITY;
#pragma unroll
  for (int off = 1; off < 8; off <<= 1) m = fmaxf(m, __shfl_xor(m, off, 64));
  float ex = act ? (__expf(v0 - m) + __expf(v1 - m) + __expf(v2 - m) + __expf(v3 - m) +
                    __expf(v4 - m) + __expf(v5 - m) + __expf(v6 - m) + __expf(v7 - m)) : 0.f;
#pragma unroll
  for (int off = 1; off < 8; off <<= 1) ex += __shfl_xor(ex, off, 64);
  if (act) {
    float lls = m + logf(ex);
    float4 s0; s0.x = v0 - lls; s0.y = v1 - lls; s0.z = v2 - lls; s0.w = v3 - lls;
    float4 s1; s1.x = v4 - lls; s1.y = v5 - lls; s1.z = v6 - lls; s1.w = v7 - lls;
    float* op = out + (size_t)node * C2 + (k << 3);
    ((float4*)op)[0] = s0; ((float4*)op)[1] = s1;
  }
}

// ---------- launch ----------
extern "C" void kernel_launch(void* const* d_in, const int* in_sizes, int n_in,
                              void* d_out, int out_size, void* d_ws, size_t ws_size,
                              hipStream_t stream) {
  const float* x    = (const float*)d_in[0];
  const float* W1   = (const float*)d_in[1];
  const float* as1w = (const float*)d_in[2];
  const float* ad1w = (const float*)d_in[3];
  const float* b1   = (const float*)d_in[4];
  const float* W2   = (const float*)d_in[5];
  const float* as2w = (const float*)d_in[6];
  const float* ad2w = (const float*)d_in[7];
  const float* b2   = (const float*)d_in[8];
  const int*   ei   = (const int*)d_in[9];

  float* out   = (float*)d_out;
  float* outls = out;                    // [N,40] log_softmax
  float* emb   = out + (long)NN * C2;    // [N,64] emb

  char* wsb = (char*)d_ws;
  __half* h1   = (__half*)wsb; wsb += sizeof(__half) * (size_t)NN * D1;
  __half* h2   = (__half*)wsb; wsb += sizeof(__half) * ((size_t)NN * H2S + 64);  // +pad
  float* asrc1 = (float*)wsb; wsb += sizeof(float) * (size_t)NN * H1;
  float* adst1 = (float*)wsb; wsb += sizeof(float) * (size_t)NN * H1;
  float* adst2 = (float*)wsb; wsb += sizeof(float) * (size_t)NN;
  int2* rowrng = (int2*)wsb;  wsb += sizeof(int2) * (size_t)NN;
  int* gcur    = (int*)wsb;   wsb += sizeof(int) * (NBKT + 4);
  int* ecsr    = (int*)wsb;   wsb += sizeof(int) * (size_t)NBKT * BCAP;

  // CSR build (bucketed, 2 kernels; per call since ws is re-poisoned)
  hipMemsetAsync(gcur, 0, sizeof(int) * (NBKT + 4), stream);
  scatter_kernel<<<NBB, 256, 0, stream>>>(ei, gcur, ecsr);
  bucket2csr_kernel<<<NBKT, 256, 0, stream>>>(gcur, rowrng, ecsr);

  // layer 1
  gemm1_kernel<<<(NN + 63) / 64, 256, 0, stream>>>(x, W1, as1w, ad1w, h1, asrc1, adst1);
  agg1_kernel<<<NN / 32, 256, 0, stream>>>(rowrng, ecsr, asrc1, adst1, h1, b1, emb);

  // layer 2 (gemm + attdot fused, as2 inlined into h2 rows)
  gemm2_kernel<<<(NN + 63) / 64, 256, 0, stream>>>(emb, W2, as2w, ad2w, h2, adst2);
  agg2_kernel<<<NN / 32, 256, 0, stream>>>(rowrng, ecsr, adst2, h2, b2, outls);
}

// Round 5
// 264.714 us; speedup vs baseline: 1.4555x; 1.1968x over previous
//
#include <hip/hip_runtime.h>
#include <hip/hip_fp16.h>
#include <math.h>

#define NN 100000
#define EE 1600000
#define ET (EE + NN)   // 1,700,000 edges incl self-loops
#define FIN 128
#define D1 64          // H1*C1
#define H1 8
#define C1 8
#define C2 40
#define NEG 0.2f
#define EPSV 1e-16f
#define LOG2E 1.4426950408889634f

#define NBKT 196       // buckets of 512 dst: (99999>>9)+1
#define BCAP 10240     // fixed bucket capacity (max count ~9200)
#define CHUNK 8192     // edges per scatter block
#define NBB ((ET + CHUNK - 1) / CHUNK)

typedef _Float16 f16x8 __attribute__((ext_vector_type(8)));
typedef float f32x4 __attribute__((ext_vector_type(4)));

__device__ __forceinline__ void edge_sd(int e, const int* __restrict__ ei, int& s, int& d) {
  if (e < EE) { s = ei[e]; d = ei[EE + e]; }
  else        { s = e - EE; d = s; }
}

// ---------- scatter edges into fixed-capacity buckets (direct reserve) ----------
__global__ __launch_bounds__(256) void scatter_kernel(const int* __restrict__ ei,
                                                      int* __restrict__ gcur,
                                                      int* __restrict__ ecsr) {
  __shared__ int lh[NBKT], lres[NBKT], lcur[NBKT];
  int t = threadIdx.x;
  if (t < NBKT) { lh[t] = 0; lcur[t] = 0; }
  __syncthreads();
  int e0 = blockIdx.x * CHUNK;
  int e1 = min(e0 + CHUNK, ET);
  for (int e = e0 + t; e < e1; e += 256) {
    int d = (e < EE) ? ei[EE + e] : e - EE;
    atomicAdd(&lh[d >> 9], 1);
  }
  __syncthreads();
  if (t < NBKT && lh[t]) lres[t] = atomicAdd(&gcur[t], lh[t]);
  __syncthreads();
  for (int e = e0 + t; e < e1; e += 256) {
    int s, d; edge_sd(e, ei, s, d);
    int b = d >> 9;
    int lp = atomicAdd(&lcur[b], 1);
    ecsr[b * BCAP + lres[b] + lp] = s | ((d & 511) << 17);
  }
}

// ---------- per-bucket: LDS-staged in-place sort -> rowrng(beg,end) + csr ----------
__global__ __launch_bounds__(256) void bucket2csr_kernel(const int* __restrict__ gcur,
                                                         int2* __restrict__ rowrng,
                                                         int* __restrict__ ecsr) {
  __shared__ int ebuf[BCAP];     // 40 KB
  __shared__ int hist[512];
  __shared__ int sd[256];
  int b = blockIdx.x, t = threadIdx.x;
  int base = b * BCAP;
  int cnt = gcur[b];
  hist[t] = 0; hist[t + 256] = 0;
  __syncthreads();
  for (int i = t; i < cnt; i += 256) {
    int p = ecsr[base + i];
    ebuf[i] = p;
    atomicAdd(&hist[p >> 17], 1);
  }
  __syncthreads();
  int h0 = hist[2 * t], h1 = hist[2 * t + 1], s = h0 + h1;
  sd[t] = s;
  __syncthreads();
  for (int off = 1; off < 256; off <<= 1) {
    int x = sd[t];
    int y = (t >= off) ? sd[t - off] : 0;
    __syncthreads();
    sd[t] = x + y;
    __syncthreads();
  }
  int run = sd[t] - s;   // exclusive base for local dst 2t
  int g = b * 512 + 2 * t;
  if (g < NN)     rowrng[g]     = make_int2(base + run,      base + run + h0);
  if (g + 1 < NN) rowrng[g + 1] = make_int2(base + run + h0, base + run + h0 + h1);
  hist[2 * t] = run;
  hist[2 * t + 1] = run + h0;
  __syncthreads();
  for (int i = t; i < cnt; i += 256) {
    int p = ebuf[i];
    int pos = atomicAdd(&hist[p >> 17], 1);
    ecsr[base + pos] = p & 0x1FFFF;
  }
}

// ---------- prep: pack W1/W2 (+folded att columns, prescaled log2e) as fp16 MFMA B-frags ----------
// Wf1 layout: [kk(4)][ct(5)][lane(64)][j(8)]; ct=4 cols: 0-7 = W1·att_s per head, 8-15 = W1·att_d
// Wf2 layout: [kk(2)][ct(3)][lane(64)][j(8)]; ct=2 col 8 = W2·att_s2, col 9 = W2·att_d2
__global__ __launch_bounds__(256) void prep_kernel(
    const float* __restrict__ W1, const float* __restrict__ as1, const float* __restrict__ ad1,
    const float* __restrict__ W2, const float* __restrict__ as2, const float* __restrict__ ad2w,
    __half* __restrict__ Wf1, __half* __restrict__ Wf2) {
  int gid = blockIdx.x * 256 + threadIdx.x;
  int stride = gridDim.x * 256;
  for (int idx = gid; idx < 4 * 5 * 64 * 8; idx += stride) {
    int j = idx & 7, l = (idx >> 3) & 63;
    int g = idx >> 9;           // kk*5+ct
    int ct = g % 5, kk = g / 5;
    int kdim = kk * 32 + (l >> 4) * 8 + j;
    int c = l & 15;
    float v;
    if (ct < 4) v = W1[kdim * 64 + ct * 16 + c];
    else {
      const float* aw = (c < 8) ? as1 : ad1;
      int hh = c & 7;
      float acc = 0.f;
      for (int q = 0; q < 8; ++q) acc += W1[kdim * 64 + hh * 8 + q] * aw[hh * 8 + q];
      v = acc * LOG2E;
    }
    Wf1[idx] = __float2half(v);
  }
  for (int idx = gid; idx < 2 * 3 * 64 * 8; idx += stride) {
    int j = idx & 7, l = (idx >> 3) & 63;
    int g = idx >> 9;           // kk*3+ct
    int ct = g % 3, kk = g / 3;
    int kdim = kk * 32 + (l >> 4) * 8 + j;
    int c = ct * 16 + (l & 15);
    float v = 0.f;
    if (c < C2) v = W2[kdim * C2 + c];
    else if (c == 40 || c == 41) {
      const float* aw = (c == 40) ? as2 : ad2w;
      float acc = 0.f;
      for (int q = 0; q < C2; ++q) acc += W2[kdim * C2 + q] * aw[q];
      v = acc * LOG2E;
    }
    Wf2[idx] = __float2half(v);
  }
}

// ---------- layer 1: MFMA GEMM (64 nodes x 80 cols incl att cols), no LDS ----------
__global__ __launch_bounds__(256) void gemm1_kernel(
    const float* __restrict__ x, const __half* __restrict__ Wf1,
    __half* __restrict__ h, __half* __restrict__ as_h, float* __restrict__ ad) {
  int t = threadIdx.x;
  int w = t >> 6, lane = t & 63;
  int col = lane & 15, kg = lane >> 4;
  int node0 = blockIdx.x * 64 + w * 16;
  int nodeA = min(node0 + col, NN - 1);    // A-row for this lane (clamped)
  const float* xr = x + (size_t)nodeA * FIN + kg * 8;
  const f16x8* Wq = (const f16x8*)Wf1;
  f32x4 acc0 = {0.f,0.f,0.f,0.f}, acc1 = acc0, acc2 = acc0, acc3 = acc0, acc4 = acc0;
#pragma unroll
  for (int kk = 0; kk < 4; ++kk) {
    float4 xa = *(const float4*)(xr + kk * 32);
    float4 xb = *(const float4*)(xr + kk * 32 + 4);
    f16x8 a;
    a[0] = (_Float16)xa.x; a[1] = (_Float16)xa.y; a[2] = (_Float16)xa.z; a[3] = (_Float16)xa.w;
    a[4] = (_Float16)xb.x; a[5] = (_Float16)xb.y; a[6] = (_Float16)xb.z; a[7] = (_Float16)xb.w;
    acc0 = __builtin_amdgcn_mfma_f32_16x16x32_f16(a, Wq[(kk * 5 + 0) * 64 + lane], acc0, 0, 0, 0);
    acc1 = __builtin_amdgcn_mfma_f32_16x16x32_f16(a, Wq[(kk * 5 + 1) * 64 + lane], acc1, 0, 0, 0);
    acc2 = __builtin_amdgcn_mfma_f32_16x16x32_f16(a, Wq[(kk * 5 + 2) * 64 + lane], acc2, 0, 0, 0);
    acc3 = __builtin_amdgcn_mfma_f32_16x16x32_f16(a, Wq[(kk * 5 + 3) * 64 + lane], acc3, 0, 0, 0);
    acc4 = __builtin_amdgcn_mfma_f32_16x16x32_f16(a, Wq[(kk * 5 + 4) * 64 + lane], acc4, 0, 0, 0);
  }
  // C/D: row = kg*4+reg (node), col = lane&15
#pragma unroll
  for (int reg = 0; reg < 4; ++reg) {
    int nr = node0 + kg * 4 + reg;
    if (nr < NN) {
      h[(size_t)nr * 64 +  0 + col] = __float2half(acc0[reg]);
      h[(size_t)nr * 64 + 16 + col] = __float2half(acc1[reg]);
      h[(size_t)nr * 64 + 32 + col] = __float2half(acc2[reg]);
      h[(size_t)nr * 64 + 48 + col] = __float2half(acc3[reg]);
      float v = acc4[reg];
      if (col < 8) as_h[nr * 8 + col] = __float2half(v);
      else         ad[nr * 8 + col - 8] = v;
    }
  }
}

// consume one edge's message (u = 8 fp16 channels, avh = src att, adv/den/a0..a7 in scope)
#define CONS(u, avh, valid) do { \
    float xx = __half2float(avh) + adv; xx = fmaxf(xx, NEG * xx); \
    float e = (valid) ? exp2f(xx) : 0.f; den += e; \
    float2 f; \
    f = __half22float2(*(const __half2*)&(u).x); a0 = fmaf(f.x, e, a0); a1 = fmaf(f.y, e, a1); \
    f = __half22float2(*(const __half2*)&(u).y); a2 = fmaf(f.x, e, a2); a3 = fmaf(f.y, e, a3); \
    f = __half22float2(*(const __half2*)&(u).z); a4 = fmaf(f.x, e, a4); a5 = fmaf(f.y, e, a5); \
    f = __half22float2(*(const __half2*)&(u).w); a6 = fmaf(f.x, e, a6); a7 = fmaf(f.y, e, a7); \
  } while (0)

// ---------- fused aggregation, layer 1: octet-per-node, ping-pong 2x8-edge batches ----------
__global__ __launch_bounds__(256) void agg1_kernel(
    const int2* __restrict__ rowrng, const int* __restrict__ csr,
    const __half* __restrict__ as_h, const float* __restrict__ ad,
    const __half* __restrict__ h, const float* __restrict__ b1,
    float* __restrict__ emb) {
  int t = threadIdx.x;
  int lane = t & 63;
  int o = lane >> 3, k = lane & 7, ob = lane & 56;
  int node = blockIdx.x * 32 + (t >> 6) * 8 + o;   // NN%32==0
  int2 rr = rowrng[node];
  int beg = rr.x, deg = rr.y - rr.x, degm1 = deg - 1;
  float adv = ad[node * 8 + k];
  float den = 0.f;
  float a0=0.f,a1=0.f,a2=0.f,a3=0.f,a4=0.f,a5=0.f,a6=0.f,a7=0.f;
  uint4 uA[8]; __half vA[8]; int sjA[8];
  int sA = csr[beg + min(k, degm1)];
#pragma unroll
  for (int r = 0; r < 8; ++r) sjA[r] = __shfl(sA, ob + r, 64);
#pragma unroll
  for (int r = 0; r < 8; ++r) {
    uA[r] = *(const uint4*)(h + ((size_t)(uint)sjA[r] << 6) + (k << 3));
    vA[r] = as_h[(uint)sjA[r] * 8u + k];
  }
  for (int i = 0; i < deg; i += 16) {
    int sB = csr[beg + min(i + 8 + k, degm1)];
    int sjB[8];
#pragma unroll
    for (int r = 0; r < 8; ++r) sjB[r] = __shfl(sB, ob + r, 64);
    uint4 uB[8]; __half vB[8];
#pragma unroll
    for (int r = 0; r < 8; ++r) {
      uB[r] = *(const uint4*)(h + ((size_t)(uint)sjB[r] << 6) + (k << 3));
      vB[r] = as_h[(uint)sjB[r] * 8u + k];
    }
#pragma unroll
    for (int r = 0; r < 8; ++r) CONS(uA[r], vA[r], i + r < deg);
    int sA2 = csr[beg + min(i + 16 + k, degm1)];
#pragma unroll
    for (int r = 0; r < 8; ++r) sjA[r] = __shfl(sA2, ob + r, 64);
#pragma unroll
    for (int r = 0; r < 8; ++r) {
      uA[r] = *(const uint4*)(h + ((size_t)(uint)sjA[r] << 6) + (k << 3));
      vA[r] = as_h[(uint)sjA[r] * 8u + k];
    }
#pragma unroll
    for (int r = 0; r < 8; ++r) CONS(uB[r], vB[r], i + 8 + r < deg);
  }
  float4 bv0 = ((const float4*)b1)[2 * k];
  float4 bv1 = ((const float4*)b1)[2 * k + 1];
  float inv = 1.0f / (den + EPSV);
  float v0 = fmaf(a0, inv, bv0.x), v1 = fmaf(a1, inv, bv0.y);
  float v2 = fmaf(a2, inv, bv0.z), v3 = fmaf(a3, inv, bv0.w);
  float v4 = fmaf(a4, inv, bv1.x), v5 = fmaf(a5, inv, bv1.y);
  float v6 = fmaf(a6, inv, bv1.z), v7 = fmaf(a7, inv, bv1.w);
  v0 = v0 > 0.f ? v0 : expm1f(v0); v1 = v1 > 0.f ? v1 : expm1f(v1);
  v2 = v2 > 0.f ? v2 : expm1f(v2); v3 = v3 > 0.f ? v3 : expm1f(v3);
  v4 = v4 > 0.f ? v4 : expm1f(v4); v5 = v5 > 0.f ? v5 : expm1f(v5);
  v6 = v6 > 0.f ? v6 : expm1f(v6); v7 = v7 > 0.f ? v7 : expm1f(v7);
  float4 s0; s0.x = v0; s0.y = v1; s0.z = v2; s0.w = v3;
  float4 s1; s1.x = v4; s1.y = v5; s1.z = v6; s1.w = v7;
  float* ep = emb + (size_t)node * D1 + (k << 3);
  ((float4*)ep)[0] = s0; ((float4*)ep)[1] = s1;
}

// ---------- layer 2: MFMA GEMM (64 nodes x 48 cols incl att cols), no LDS ----------
// h2 row = 64 halfs (128B aligned line): cols 0-39 = channels, [40] = as2 (half)
__global__ __launch_bounds__(256) void gemm2_kernel(
    const float* __restrict__ emb, const __half* __restrict__ Wf2,
    __half* __restrict__ h2, float* __restrict__ ad2) {
  int t = threadIdx.x;
  int w = t >> 6, lane = t & 63;
  int col = lane & 15, kg = lane >> 4;
  int node0 = blockIdx.x * 64 + w * 16;
  int nodeA = min(node0 + col, NN - 1);
  const float* er = emb + (size_t)nodeA * D1 + kg * 8;
  const f16x8* Wq = (const f16x8*)Wf2;
  f32x4 acc0 = {0.f,0.f,0.f,0.f}, acc1 = acc0, acc2 = acc0;
#pragma unroll
  for (int kk = 0; kk < 2; ++kk) {
    float4 xa = *(const float4*)(er + kk * 32);
    float4 xb = *(const float4*)(er + kk * 32 + 4);
    f16x8 a;
    a[0] = (_Float16)xa.x; a[1] = (_Float16)xa.y; a[2] = (_Float16)xa.z; a[3] = (_Float16)xa.w;
    a[4] = (_Float16)xb.x; a[5] = (_Float16)xb.y; a[6] = (_Float16)xb.z; a[7] = (_Float16)xb.w;
    acc0 = __builtin_amdgcn_mfma_f32_16x16x32_f16(a, Wq[(kk * 3 + 0) * 64 + lane], acc0, 0, 0, 0);
    acc1 = __builtin_amdgcn_mfma_f32_16x16x32_f16(a, Wq[(kk * 3 + 1) * 64 + lane], acc1, 0, 0, 0);
    acc2 = __builtin_amdgcn_mfma_f32_16x16x32_f16(a, Wq[(kk * 3 + 2) * 64 + lane], acc2, 0, 0, 0);
  }
#pragma unroll
  for (int reg = 0; reg < 4; ++reg) {
    int nr = node0 + kg * 4 + reg;
    if (nr < NN) {
      h2[(size_t)nr * 64 +  0 + col] = __float2half(acc0[reg]);
      h2[(size_t)nr * 64 + 16 + col] = __float2half(acc1[reg]);
      float v = acc2[reg];
      if (col < 8)       h2[(size_t)nr * 64 + 32 + col] = __float2half(v);
      else if (col == 8) h2[(size_t)nr * 64 + 40] = __float2half(v);
      else if (col == 9) ad2[nr] = v;
    }
  }
}

// ---------- fused aggregation, layer 2 + log_softmax: octet-per-node, ping-pong ----------
__global__ __launch_bounds__(256) void agg2_kernel(
    const int2* __restrict__ rowrng, const int* __restrict__ csr,
    const float* __restrict__ ad, const __half* __restrict__ h2,
    const float* __restrict__ b2, float* __restrict__ out) {
  int t = threadIdx.x;
  int lane = t & 63;
  int o = lane >> 3, k = lane & 7, ob = lane & 56;
  int kc = min(k, 4);
  int node = blockIdx.x * 32 + (t >> 6) * 8 + o;
  int2 rr = rowrng[node];
  int beg = rr.x, deg = rr.y - rr.x, degm1 = deg - 1;
  float adv = ad[node];
  float den = 0.f;
  float a0=0.f,a1=0.f,a2=0.f,a3=0.f,a4=0.f,a5=0.f,a6=0.f,a7=0.f;
  uint4 uA[8]; __half vA[8]; int sjA[8];
  int sA = csr[beg + min(k, degm1)];
#pragma unroll
  for (int r = 0; r < 8; ++r) sjA[r] = __shfl(sA, ob + r, 64);
#pragma unroll
  for (int r = 0; r < 8; ++r) {
    const __half* rp = h2 + ((size_t)(uint)sjA[r] << 6);
    uA[r] = *(const uint4*)(rp + (kc << 3));
    vA[r] = rp[40];
  }
  for (int i = 0; i < deg; i += 16) {
    int sB = csr[beg + min(i + 8 + k, degm1)];
    int sjB[8];
#pragma unroll
    for (int r = 0; r < 8; ++r) sjB[r] = __shfl(sB, ob + r, 64);
    uint4 uB[8]; __half vB[8];
#pragma unroll
    for (int r = 0; r < 8; ++r) {
      const __half* rp = h2 + ((size_t)(uint)sjB[r] << 6);
      uB[r] = *(const uint4*)(rp + (kc << 3));
      vB[r] = rp[40];
    }
#pragma unroll
    for (int r = 0; r < 8; ++r) CONS(uA[r], vA[r], i + r < deg);
    int sA2 = csr[beg + min(i + 16 + k, degm1)];
#pragma unroll
    for (int r = 0; r < 8; ++r) sjA[r] = __shfl(sA2, ob + r, 64);
#pragma unroll
    for (int r = 0; r < 8; ++r) {
      const __half* rp = h2 + ((size_t)(uint)sjA[r] << 6);
      uA[r] = *(const uint4*)(rp + (kc << 3));
      vA[r] = rp[40];
    }
#pragma unroll
    for (int r = 0; r < 8; ++r) CONS(uB[r], vB[r], i + 8 + r < deg);
  }
  float4 bv0 = ((const float4*)b2)[2 * kc];
  float4 bv1 = ((const float4*)b2)[2 * kc + 1];
  float inv = 1.0f / (den + EPSV);
  float v0 = fmaf(a0, inv, bv0.x), v1 = fmaf(a1, inv, bv0.y);
  float v2 = fmaf(a2, inv, bv0.z), v3 = fmaf(a3, inv, bv0.w);
  float v4 = fmaf(a4, inv, bv1.x), v5 = fmaf(a5, inv, bv1.y);
  float v6 = fmaf(a6, inv, bv1.z), v7 = fmaf(a7, inv, bv1.w);
  bool act = (k < 5);
  float m = act ? fmaxf(fmaxf(fmaxf(v0, v1), fmaxf(v2, v3)),
                        fmaxf(fmaxf(v4, v5), fmaxf(v6, v7))) : -INFINITY;
#pragma unroll
  for (int off = 1; off < 8; off <<= 1) m = fmaxf(m, __shfl_xor(m, off, 64));
  float ex = act ? (__expf(v0 - m) + __expf(v1 - m) + __expf(v2 - m) + __expf(v3 - m) +
                    __expf(v4 - m) + __expf(v5 - m) + __expf(v6 - m) + __expf(v7 - m)) : 0.f;
#pragma unroll
  for (int off = 1; off < 8; off <<= 1) ex += __shfl_xor(ex, off, 64);
  if (act) {
    float lls = m + logf(ex);
    float4 s0; s0.x = v0 - lls; s0.y = v1 - lls; s0.z = v2 - lls; s0.w = v3 - lls;
    float4 s1; s1.x = v4 - lls; s1.y = v5 - lls; s1.z = v6 - lls; s1.w = v7 - lls;
    float* op = out + (size_t)node * C2 + (k << 3);
    ((float4*)op)[0] = s0; ((float4*)op)[1] = s1;
  }
}

// ---------- launch ----------
extern "C" void kernel_launch(void* const* d_in, const int* in_sizes, int n_in,
                              void* d_out, int out_size, void* d_ws, size_t ws_size,
                              hipStream_t stream) {
  const float* x    = (const float*)d_in[0];
  const float* W1   = (const float*)d_in[1];
  const float* as1w = (const float*)d_in[2];
  const float* ad1w = (const float*)d_in[3];
  const float* b1   = (const float*)d_in[4];
  const float* W2   = (const float*)d_in[5];
  const float* as2w = (const float*)d_in[6];
  const float* ad2w = (const float*)d_in[7];
  const float* b2   = (const float*)d_in[8];
  const int*   ei   = (const int*)d_in[9];

  float* out   = (float*)d_out;
  float* outls = out;                    // [N,40] log_softmax
  float* emb   = out + (long)NN * C2;    // [N,64] emb

  char* wsb = (char*)d_ws;
  __half* h1   = (__half*)wsb; wsb += sizeof(__half) * (size_t)NN * D1;
  __half* h2   = (__half*)wsb; wsb += sizeof(__half) * ((size_t)NN * 64 + 64);
  __half* ash1 = (__half*)wsb; wsb += sizeof(__half) * (size_t)NN * H1;
  float* adst1 = (float*)wsb; wsb += sizeof(float) * (size_t)NN * H1;
  float* adst2 = (float*)wsb; wsb += sizeof(float) * (size_t)NN;
  int2* rowrng = (int2*)wsb;  wsb += sizeof(int2) * (size_t)NN;
  int* gcur    = (int*)wsb;   wsb += sizeof(int) * (NBKT + 4);
  __half* Wf1  = (__half*)wsb; wsb += sizeof(__half) * 4 * 5 * 64 * 8;
  __half* Wf2  = (__half*)wsb; wsb += sizeof(__half) * 2 * 3 * 64 * 8;
  int* ecsr    = (int*)wsb;   wsb += sizeof(int) * (size_t)NBKT * BCAP;

  // weight prep (tiny) + CSR build
  prep_kernel<<<16, 256, 0, stream>>>(W1, as1w, ad1w, W2, as2w, ad2w, Wf1, Wf2);
  hipMemsetAsync(gcur, 0, sizeof(int) * (NBKT + 4), stream);
  scatter_kernel<<<NBB, 256, 0, stream>>>(ei, gcur, ecsr);
  bucket2csr_kernel<<<NBKT, 256, 0, stream>>>(gcur, rowrng, ecsr);

  // layer 1
  gemm1_kernel<<<(NN + 63) / 64, 256, 0, stream>>>(x, Wf1, h1, ash1, adst1);
  agg1_kernel<<<NN / 32, 256, 0, stream>>>(rowrng, ecsr, ash1, adst1, h1, b1, emb);

  // layer 2
  gemm2_kernel<<<(NN + 63) / 64, 256, 0, stream>>>(emb, Wf2, h2, adst2);
  agg2_kernel<<<NN / 32, 256, 0, stream>>>(rowrng, ecsr, adst2, h2, b2, outls);
}

// Round 6
// 257.508 us; speedup vs baseline: 1.4962x; 1.0280x over previous
//
#include <hip/hip_runtime.h>
#include <hip/hip_fp16.h>
#include <math.h>

#define NN 100000
#define EE 1600000
#define ET (EE + NN)   // 1,700,000 edges incl self-loops
#define FIN 128
#define D1 64          // H1*C1
#define H1 8
#define C1 8
#define C2 40
#define NEG 0.2f
#define EPSV 1e-16f
#define LOG2E 1.4426950408889634f

#define NBKT 391       // buckets of 256 dst: (99999>>8)+1
#define BCAP 5120      // fixed bucket capacity (mean 4352, sigma ~66)
#define CHUNK 2048     // edges per scatter block
#define NBB ((ET + CHUNK - 1) / CHUNK)   // 830
#define G1B ((NN + 63) / 64)             // 1563
#define PREPB 16

typedef _Float16 f16x8 __attribute__((ext_vector_type(8)));
typedef float f32x4 __attribute__((ext_vector_type(4)));

__device__ __forceinline__ void edge_sd(int e, const int* __restrict__ ei, int& s, int& d) {
  if (e < EE) { s = ei[e]; d = ei[EE + e]; }
  else        { s = e - EE; d = s; }
}

// ---------- k1: scatter (blocks 0..NBB-1) || weight prep (blocks NBB..) ----------
// scatter: edges -> fixed-capacity dst/256 buckets, packed s | ((d&255)<<17)
// prep: Wf1 [kk(4)][ct(5)][lane(64)][j(8)], Wf2 [kk(2)][ct(3)][lane(64)][j(8)]
__global__ __launch_bounds__(256) void k1_kernel(
    const int* __restrict__ ei, int* __restrict__ gcur, int* __restrict__ ecsr,
    const float* __restrict__ W1, const float* __restrict__ as1, const float* __restrict__ ad1,
    const float* __restrict__ W2, const float* __restrict__ as2, const float* __restrict__ ad2w,
    __half* __restrict__ Wf1, __half* __restrict__ Wf2) {
  __shared__ int lh[NBKT], lres[NBKT], lcur[NBKT];
  int t = threadIdx.x;
  if (blockIdx.x < NBB) {
    // ---- scatter ----
    for (int i = t; i < NBKT; i += 256) { lh[i] = 0; lcur[i] = 0; }
    __syncthreads();
    int e0 = blockIdx.x * CHUNK;
    int e1 = min(e0 + CHUNK, ET);
    for (int e = e0 + t; e < e1; e += 256) {
      int d = (e < EE) ? ei[EE + e] : e - EE;
      atomicAdd(&lh[d >> 8], 1);
    }
    __syncthreads();
    for (int i = t; i < NBKT; i += 256)
      if (lh[i]) lres[i] = atomicAdd(&gcur[i], lh[i]);
    __syncthreads();
    for (int e = e0 + t; e < e1; e += 256) {
      int s, d; edge_sd(e, ei, s, d);
      int b = d >> 8;
      int lp = atomicAdd(&lcur[b], 1);
      ecsr[b * BCAP + lres[b] + lp] = s | ((d & 255) << 17);
    }
  } else {
    // ---- prep ----
    int gid = (blockIdx.x - NBB) * 256 + t;
    int stride = PREPB * 256;
    for (int idx = gid; idx < 4 * 5 * 64 * 8; idx += stride) {
      int j = idx & 7, l = (idx >> 3) & 63;
      int g = idx >> 9;           // kk*5+ct
      int ct = g % 5, kk = g / 5;
      int kdim = kk * 32 + (l >> 4) * 8 + j;
      int c = l & 15;
      float v;
      if (ct < 4) v = W1[kdim * 64 + ct * 16 + c];
      else {
        const float* aw = (c < 8) ? as1 : ad1;
        int hh = c & 7;
        float acc = 0.f;
        for (int q = 0; q < 8; ++q) acc += W1[kdim * 64 + hh * 8 + q] * aw[hh * 8 + q];
        v = acc * LOG2E;
      }
      Wf1[idx] = __float2half(v);
    }
    for (int idx = gid; idx < 2 * 3 * 64 * 8; idx += stride) {
      int j = idx & 7, l = (idx >> 3) & 63;
      int g = idx >> 9;           // kk*3+ct
      int ct = g % 3, kk = g / 3;
      int kdim = kk * 32 + (l >> 4) * 8 + j;
      int c = ct * 16 + (l & 15);
      float v = 0.f;
      if (c < C2) v = W2[kdim * C2 + c];
      else if (c == 40 || c == 41) {
        const float* aw = (c == 40) ? as2 : ad2w;
        float acc = 0.f;
        for (int q = 0; q < C2; ++q) acc += W2[kdim * C2 + q] * aw[q];
        v = acc * LOG2E;
      }
      Wf2[idx] = __float2half(v);
    }
  }
}

// ---------- k2: bucket2csr (blocks 0..NBKT-1) || MFMA gemm1 (blocks NBKT..) ----------
__global__ __launch_bounds__(256) void k2_kernel(
    const int* __restrict__ gcur, int2* __restrict__ rowrng, int* __restrict__ ecsr,
    const float* __restrict__ x, const __half* __restrict__ Wf1,
    __half* __restrict__ h, __half* __restrict__ as_h, float* __restrict__ ad) {
  __shared__ int ebuf[BCAP];     // 20 KB
  __shared__ int hist[256];
  __shared__ int sd[256];
  int t = threadIdx.x;
  if (blockIdx.x < NBKT) {
    // ---- bucket2csr: LDS-staged in-place counting sort, thread t owns dst t ----
    int b = blockIdx.x;
    int base = b * BCAP;
    int cnt = gcur[b];
    hist[t] = 0;
    __syncthreads();
    for (int i = t; i < cnt; i += 256) {
      int p = ecsr[base + i];
      ebuf[i] = p;
      atomicAdd(&hist[p >> 17], 1);
    }
    __syncthreads();
    int h0 = hist[t];
    sd[t] = h0;
    __syncthreads();
    for (int off = 1; off < 256; off <<= 1) {
      int xv = sd[t];
      int yv = (t >= off) ? sd[t - off] : 0;
      __syncthreads();
      sd[t] = xv + yv;
      __syncthreads();
    }
    int run = sd[t] - h0;   // exclusive base for local dst t
    int g = b * 256 + t;
    if (g < NN) rowrng[g] = make_int2(base + run, base + run + h0);
    hist[t] = run;
    __syncthreads();
    for (int i = t; i < cnt; i += 256) {
      int p = ebuf[i];
      int pos = atomicAdd(&hist[p >> 17], 1);
      ecsr[base + pos] = p & 0x1FFFF;
    }
  } else {
    // ---- gemm1: MFMA 64 nodes x 80 cols (64 ch + 16 att cols), no staging ----
    int blk = blockIdx.x - NBKT;
    int w = t >> 6, lane = t & 63;
    int col = lane & 15, kg = lane >> 4;
    int node0 = blk * 64 + w * 16;
    int nodeA = min(node0 + col, NN - 1);
    const float* xr = x + (size_t)nodeA * FIN + kg * 8;
    const f16x8* Wq = (const f16x8*)Wf1;
    f32x4 acc0 = {0.f,0.f,0.f,0.f}, acc1 = acc0, acc2 = acc0, acc3 = acc0, acc4 = acc0;
#pragma unroll
    for (int kk = 0; kk < 4; ++kk) {
      float4 xa = *(const float4*)(xr + kk * 32);
      float4 xb = *(const float4*)(xr + kk * 32 + 4);
      f16x8 a;
      a[0] = (_Float16)xa.x; a[1] = (_Float16)xa.y; a[2] = (_Float16)xa.z; a[3] = (_Float16)xa.w;
      a[4] = (_Float16)xb.x; a[5] = (_Float16)xb.y; a[6] = (_Float16)xb.z; a[7] = (_Float16)xb.w;
      acc0 = __builtin_amdgcn_mfma_f32_16x16x32_f16(a, Wq[(kk * 5 + 0) * 64 + lane], acc0, 0, 0, 0);
      acc1 = __builtin_amdgcn_mfma_f32_16x16x32_f16(a, Wq[(kk * 5 + 1) * 64 + lane], acc1, 0, 0, 0);
      acc2 = __builtin_amdgcn_mfma_f32_16x16x32_f16(a, Wq[(kk * 5 + 2) * 64 + lane], acc2, 0, 0, 0);
      acc3 = __builtin_amdgcn_mfma_f32_16x16x32_f16(a, Wq[(kk * 5 + 3) * 64 + lane], acc3, 0, 0, 0);
      acc4 = __builtin_amdgcn_mfma_f32_16x16x32_f16(a, Wq[(kk * 5 + 4) * 64 + lane], acc4, 0, 0, 0);
    }
#pragma unroll
    for (int reg = 0; reg < 4; ++reg) {
      int nr = node0 + kg * 4 + reg;
      if (nr < NN) {
        h[(size_t)nr * 64 +  0 + col] = __float2half(acc0[reg]);
        h[(size_t)nr * 64 + 16 + col] = __float2half(acc1[reg]);
        h[(size_t)nr * 64 + 32 + col] = __float2half(acc2[reg]);
        h[(size_t)nr * 64 + 48 + col] = __float2half(acc3[reg]);
        float v = acc4[reg];
        if (col < 8) as_h[nr * 8 + col] = __float2half(v);
        else         ad[nr * 8 + col - 8] = v;
      }
    }
  }
}

// consume one edge's message (u = 8 fp16 channels, avh = src att, adv/den/a0..a7 in scope)
#define CONS(u, avh, valid) do { \
    float xx = __half2float(avh) + adv; xx = fmaxf(xx, NEG * xx); \
    float e = (valid) ? exp2f(xx) : 0.f; den += e; \
    float2 f; \
    f = __half22float2(*(const __half2*)&(u).x); a0 = fmaf(f.x, e, a0); a1 = fmaf(f.y, e, a1); \
    f = __half22float2(*(const __half2*)&(u).y); a2 = fmaf(f.x, e, a2); a3 = fmaf(f.y, e, a3); \
    f = __half22float2(*(const __half2*)&(u).z); a4 = fmaf(f.x, e, a4); a5 = fmaf(f.y, e, a5); \
    f = __half22float2(*(const __half2*)&(u).w); a6 = fmaf(f.x, e, a6); a7 = fmaf(f.y, e, a7); \
  } while (0)

// ---------- fused aggregation, layer 1: octet-per-node, guarded 8-edge batches ----------
__global__ __launch_bounds__(256) void agg1_kernel(
    const int2* __restrict__ rowrng, const int* __restrict__ csr,
    const __half* __restrict__ as_h, const float* __restrict__ ad,
    const __half* __restrict__ h, const float* __restrict__ b1,
    float* __restrict__ emb) {
  int t = threadIdx.x;
  int lane = t & 63;
  int o = lane >> 3, k = lane & 7, ob = lane & 56;
  int node = blockIdx.x * 32 + (t >> 6) * 8 + o;   // NN%32==0
  int2 rr = rowrng[node];
  int beg = rr.x, deg = rr.y - rr.x, degm1 = deg - 1;
  float adv = ad[node * 8 + k];
  float den = 0.f;
  float a0=0.f,a1=0.f,a2=0.f,a3=0.f,a4=0.f,a5=0.f,a6=0.f,a7=0.f;
  uint4 uA[8]; __half vA[8];
  {
    int sA = csr[beg + min(k, degm1)];
#pragma unroll
    for (int r = 0; r < 8; ++r) {
      int sj = __shfl(sA, ob + r, 64);
      uA[r] = *(const uint4*)(h + ((size_t)(uint)sj << 6) + (k << 3));
      vA[r] = as_h[(uint)sj * 8u + k];
    }
  }
  for (int i = 0; i < deg; i += 16) {
    uint4 uB[8]; __half vB[8];
    bool haveB = (i + 8 < deg);      // uniform within octet
    if (haveB) {
      int sB = csr[beg + min(i + 8 + k, degm1)];
#pragma unroll
      for (int r = 0; r < 8; ++r) {
        int sj = __shfl(sB, ob + r, 64);
        uB[r] = *(const uint4*)(h + ((size_t)(uint)sj << 6) + (k << 3));
        vB[r] = as_h[(uint)sj * 8u + k];
      }
    }
#pragma unroll
    for (int r = 0; r < 8; ++r) CONS(uA[r], vA[r], i + r < deg);
    if (i + 16 < deg) {
      int sA2 = csr[beg + min(i + 16 + k, degm1)];
#pragma unroll
      for (int r = 0; r < 8; ++r) {
        int sj = __shfl(sA2, ob + r, 64);
        uA[r] = *(const uint4*)(h + ((size_t)(uint)sj << 6) + (k << 3));
        vA[r] = as_h[(uint)sj * 8u + k];
      }
    }
    if (haveB) {
#pragma unroll
      for (int r = 0; r < 8; ++r) CONS(uB[r], vB[r], i + 8 + r < deg);
    }
  }
  float4 bv0 = ((const float4*)b1)[2 * k];
  float4 bv1 = ((const float4*)b1)[2 * k + 1];
  float inv = 1.0f / (den + EPSV);
  float v0 = fmaf(a0, inv, bv0.x), v1 = fmaf(a1, inv, bv0.y);
  float v2 = fmaf(a2, inv, bv0.z), v3 = fmaf(a3, inv, bv0.w);
  float v4 = fmaf(a4, inv, bv1.x), v5 = fmaf(a5, inv, bv1.y);
  float v6 = fmaf(a6, inv, bv1.z), v7 = fmaf(a7, inv, bv1.w);
  v0 = v0 > 0.f ? v0 : expm1f(v0); v1 = v1 > 0.f ? v1 : expm1f(v1);
  v2 = v2 > 0.f ? v2 : expm1f(v2); v3 = v3 > 0.f ? v3 : expm1f(v3);
  v4 = v4 > 0.f ? v4 : expm1f(v4); v5 = v5 > 0.f ? v5 : expm1f(v5);
  v6 = v6 > 0.f ? v6 : expm1f(v6); v7 = v7 > 0.f ? v7 : expm1f(v7);
  float4 s0; s0.x = v0; s0.y = v1; s0.z = v2; s0.w = v3;
  float4 s1; s1.x = v4; s1.y = v5; s1.z = v6; s1.w = v7;
  float* ep = emb + (size_t)node * D1 + (k << 3);
  ((float4*)ep)[0] = s0; ((float4*)ep)[1] = s1;
}

// ---------- layer 2: MFMA GEMM (64 nodes x 48 cols incl att cols), no LDS ----------
// h2 row = 64 halfs (one 128B line): cols 0-39 = channels, [40] = as2 (half)
__global__ __launch_bounds__(256) void gemm2_kernel(
    const float* __restrict__ emb, const __half* __restrict__ Wf2,
    __half* __restrict__ h2, float* __restrict__ ad2) {
  int t = threadIdx.x;
  int w = t >> 6, lane = t & 63;
  int col = lane & 15, kg = lane >> 4;
  int node0 = blockIdx.x * 64 + w * 16;
  int nodeA = min(node0 + col, NN - 1);
  const float* er = emb + (size_t)nodeA * D1 + kg * 8;
  const f16x8* Wq = (const f16x8*)Wf2;
  f32x4 acc0 = {0.f,0.f,0.f,0.f}, acc1 = acc0, acc2 = acc0;
#pragma unroll
  for (int kk = 0; kk < 2; ++kk) {
    float4 xa = *(const float4*)(er + kk * 32);
    float4 xb = *(const float4*)(er + kk * 32 + 4);
    f16x8 a;
    a[0] = (_Float16)xa.x; a[1] = (_Float16)xa.y; a[2] = (_Float16)xa.z; a[3] = (_Float16)xa.w;
    a[4] = (_Float16)xb.x; a[5] = (_Float16)xb.y; a[6] = (_Float16)xb.z; a[7] = (_Float16)xb.w;
    acc0 = __builtin_amdgcn_mfma_f32_16x16x32_f16(a, Wq[(kk * 3 + 0) * 64 + lane], acc0, 0, 0, 0);
    acc1 = __builtin_amdgcn_mfma_f32_16x16x32_f16(a, Wq[(kk * 3 + 1) * 64 + lane], acc1, 0, 0, 0);
    acc2 = __builtin_amdgcn_mfma_f32_16x16x32_f16(a, Wq[(kk * 3 + 2) * 64 + lane], acc2, 0, 0, 0);
  }
#pragma unroll
  for (int reg = 0; reg < 4; ++reg) {
    int nr = node0 + kg * 4 + reg;
    if (nr < NN) {
      h2[(size_t)nr * 64 +  0 + col] = __float2half(acc0[reg]);
      h2[(size_t)nr * 64 + 16 + col] = __float2half(acc1[reg]);
      float v = acc2[reg];
      if (col < 8)       h2[(size_t)nr * 64 + 32 + col] = __float2half(v);
      else if (col == 8) h2[(size_t)nr * 64 + 40] = __float2half(v);
      else if (col == 9) ad2[nr] = v;
    }
  }
}

// ---------- fused aggregation, layer 2 + log_softmax: octet-per-node, guarded ----------
__global__ __launch_bounds__(256) void agg2_kernel(
    const int2* __restrict__ rowrng, const int* __restrict__ csr,
    const float* __restrict__ ad, const __half* __restrict__ h2,
    const float* __restrict__ b2, float* __restrict__ out) {
  int t = threadIdx.x;
  int lane = t & 63;
  int o = lane >> 3, k = lane & 7, ob = lane & 56;
  int kc = min(k, 4);
  int node = blockIdx.x * 32 + (t >> 6) * 8 + o;
  int2 rr = rowrng[node];
  int beg = rr.x, deg = rr.y - rr.x, degm1 = deg - 1;
  float adv = ad[node];
  float den = 0.f;
  float a0=0.f,a1=0.f,a2=0.f,a3=0.f,a4=0.f,a5=0.f,a6=0.f,a7=0.f;
  uint4 uA[8]; __half vA[8];
  {
    int sA = csr[beg + min(k, degm1)];
#pragma unroll
    for (int r = 0; r < 8; ++r) {
      int sj = __shfl(sA, ob + r, 64);
      const __half* rp = h2 + ((size_t)(uint)sj << 6);
      uA[r] = *(const uint4*)(rp + (kc << 3));
      vA[r] = rp[40];
    }
  }
  for (int i = 0; i < deg; i += 16) {
    uint4 uB[8]; __half vB[8];
    bool haveB = (i + 8 < deg);
    if (haveB) {
      int sB = csr[beg + min(i + 8 + k, degm1)];
#pragma unroll
      for (int r = 0; r < 8; ++r) {
        int sj = __shfl(sB, ob + r, 64);
        const __half* rp = h2 + ((size_t)(uint)sj << 6);
        uB[r] = *(const uint4*)(rp + (kc << 3));
        vB[r] = rp[40];
      }
    }
#pragma unroll
    for (int r = 0; r < 8; ++r) CONS(uA[r], vA[r], i + r < deg);
    if (i + 16 < deg) {
      int sA2 = csr[beg + min(i + 16 + k, degm1)];
#pragma unroll
      for (int r = 0; r < 8; ++r) {
        int sj = __shfl(sA2, ob + r, 64);
        const __half* rp = h2 + ((size_t)(uint)sj << 6);
        uA[r] = *(const uint4*)(rp + (kc << 3));
        vA[r] = rp[40];
      }
    }
    if (haveB) {
#pragma unroll
      for (int r = 0; r < 8; ++r) CONS(uB[r], vB[r], i + 8 + r < deg);
    }
  }
  float4 bv0 = ((const float4*)b2)[2 * kc];
  float4 bv1 = ((const float4*)b2)[2 * kc + 1];
  float inv = 1.0f / (den + EPSV);
  float v0 = fmaf(a0, inv, bv0.x), v1 = fmaf(a1, inv, bv0.y);
  float v2 = fmaf(a2, inv, bv0.z), v3 = fmaf(a3, inv, bv0.w);
  float v4 = fmaf(a4, inv, bv1.x), v5 = fmaf(a5, inv, bv1.y);
  float v6 = fmaf(a6, inv, bv1.z), v7 = fmaf(a7, inv, bv1.w);
  bool act = (k < 5);
  float m = act ? fmaxf(fmaxf(fmaxf(v0, v1), fmaxf(v2, v3)),
                        fmaxf(fmaxf(v4, v5), fmaxf(v6, v7))) : -INFINITY;
#pragma unroll
  for (int off = 1; off < 8; off <<= 1) m = fmaxf(m, __shfl_xor(m, off, 64));
  float ex = act ? (__expf(v0 - m) + __expf(v1 - m) + __expf(v2 - m) + __expf(v3 - m) +
                    __expf(v4 - m) + __expf(v5 - m) + __expf(v6 - m) + __expf(v7 - m)) : 0.f;
#pragma unroll
  for (int off = 1; off < 8; off <<= 1) ex += __shfl_xor(ex, off, 64);
  if (act) {
    float lls = m + logf(ex);
    float4 s0; s0.x = v0 - lls; s0.y = v1 - lls; s0.z = v2 - lls; s0.w = v3 - lls;
    float4 s1; s1.x = v4 - lls; s1.y = v5 - lls; s1.z = v6 - lls; s1.w = v7 - lls;
    float* op = out + (size_t)node * C2 + (k << 3);
    ((float4*)op)[0] = s0; ((float4*)op)[1] = s1;
  }
}

// ---------- launch ----------
extern "C" void kernel_launch(void* const* d_in, const int* in_sizes, int n_in,
                              void* d_out, int out_size, void* d_ws, size_t ws_size,
                              hipStream_t stream) {
  const float* x    = (const float*)d_in[0];
  const float* W1   = (const float*)d_in[1];
  const float* as1w = (const float*)d_in[2];
  const float* ad1w = (const float*)d_in[3];
  const float* b1   = (const float*)d_in[4];
  const float* W2   = (const float*)d_in[5];
  const float* as2w = (const float*)d_in[6];
  const float* ad2w = (const float*)d_in[7];
  const float* b2   = (const float*)d_in[8];
  const int*   ei   = (const int*)d_in[9];

  float* out   = (float*)d_out;
  float* outls = out;                    // [N,40] log_softmax
  float* emb   = out + (long)NN * C2;    // [N,64] emb

  char* wsb = (char*)d_ws;
  __half* h1   = (__half*)wsb; wsb += sizeof(__half) * (size_t)NN * D1;
  __half* h2   = (__half*)wsb; wsb += sizeof(__half) * ((size_t)NN * 64 + 64);
  __half* ash1 = (__half*)wsb; wsb += sizeof(__half) * (size_t)NN * H1;
  float* adst1 = (float*)wsb; wsb += sizeof(float) * (size_t)NN * H1;
  float* adst2 = (float*)wsb; wsb += sizeof(float) * (size_t)NN;
  int2* rowrng = (int2*)wsb;  wsb += sizeof(int2) * (size_t)NN;
  int* gcur    = (int*)wsb;   wsb += sizeof(int) * (NBKT + 4);
  __half* Wf1  = (__half*)wsb; wsb += sizeof(__half) * 4 * 5 * 64 * 8;
  __half* Wf2  = (__half*)wsb; wsb += sizeof(__half) * 2 * 3 * 64 * 8;
  int* ecsr    = (int*)wsb;   wsb += sizeof(int) * (size_t)NBKT * BCAP;

  hipMemsetAsync(gcur, 0, sizeof(int) * (NBKT + 4), stream);
  // k1: scatter || prep
  k1_kernel<<<NBB + PREPB, 256, 0, stream>>>(ei, gcur, ecsr,
                                             W1, as1w, ad1w, W2, as2w, ad2w, Wf1, Wf2);
  // k2: bucket2csr || gemm1
  k2_kernel<<<NBKT + G1B, 256, 0, stream>>>(gcur, rowrng, ecsr, x, Wf1, h1, ash1, adst1);
  // layer-1 aggregation
  agg1_kernel<<<NN / 32, 256, 0, stream>>>(rowrng, ecsr, ash1, adst1, h1, b1, emb);
  // layer 2
  gemm2_kernel<<<(NN + 63) / 64, 256, 0, stream>>>(emb, Wf2, h2, adst2);
  agg2_kernel<<<NN / 32, 256, 0, stream>>>(rowrng, ecsr, adst2, h2, b2, outls);
}